// Round 14
// baseline (261.686 us; speedup 1.0000x reference)
//
#include <hip/hip_runtime.h>
#include <hip/hip_fp16.h>
#include <math.h>

static constexpr int N = 100000;
static constexpr int SHIFT = 7;                        // 128 nodes / bucket
static constexpr int BUCKN = 1 << SHIFT;               // 128
static constexpr int NBUCK = (N + BUCKN - 1) >> SHIFT; // 782
static constexpr int HDRS  = NBUCK + 1;                // 783 offsets per block
static constexpr int CHUNK = 8192;                     // edges per partition block
static constexpr int BPMAX = 512;                      // max partition blocks supported
static constexpr int STRIDE = 5120;                    // per-bucket CSR capacity (16 sigma)
static constexpr int COLCAP = NBUCK * STRIDE;
static constexpr int ES_CAP = STRIDE;

// ---------------- partition: per-block LDS counting sort, COALESCED writes ----------------
// Block b sorts its CHUNK edges by bucket in LDS, writes them back to its OWN
// region col[b*CHUNK ...] (sequential stores, no write amplification), plus a
// header of per-bucket start offsets. No global atomics, no cross-block cursors.
__global__ __launch_bounds__(1024) void k_part(const int* __restrict__ src,
                                               const int* __restrict__ dst,
                                               int* __restrict__ col,
                                               int* __restrict__ hdr, int E) {
    __shared__ int stage[CHUNK];     // 32 KB
    __shared__ int hl[NBUCK];
    __shared__ int cur[NBUCK];
    __shared__ int s[1024];
    const int t = threadIdx.x, b = blockIdx.x;
    if (t < NBUCK) hl[t] = 0;        // 1024 >= NBUCK: single-shot OK
    __syncthreads();
    const int e0 = b * CHUNK;
    const int m = min(CHUNK, E - e0);
    for (int i = t; i < m; i += 1024) atomicAdd(&hl[dst[e0 + i] >> SHIFT], 1);
    __syncthreads();
    int v = (t < NBUCK) ? hl[t] : 0;
    s[t] = v;
    __syncthreads();
    for (int off = 1; off < 1024; off <<= 1) {
        int u = (t >= off) ? s[t - off] : 0;
        __syncthreads();
        s[t] += u;
        __syncthreads();
    }
    if (t < NBUCK) {
        int excl = s[t] - v;
        cur[t] = excl;
        hdr[b * HDRS + t] = excl;
    }
    if (t == 0) hdr[b * HDRS + NBUCK] = m;
    __syncthreads();
    for (int i = t; i < m; i += 1024) {
        int d = dst[e0 + i];
        int pos = atomicAdd(&cur[d >> SHIFT], 1);
        pos = min(max(pos, 0), CHUNK - 1);               // safety clamp (no-op)
        stage[pos] = (src[e0 + i] & 0x1FFFF) | ((d & (BUCKN - 1)) << 17);
    }
    __syncthreads();
    for (int i = t; i < m; i += 1024) col[e0 + i] = stage[i];   // sequential
}

// ---------------- per-bucket: gather runs from all blocks, sort -> CSR in col2 ----------------
__global__ __launch_bounds__(1024) void k_sort(const int* __restrict__ col,
                                               const int* __restrict__ hdr,
                                               int* __restrict__ col2,
                                               int* __restrict__ deg,
                                               int* __restrict__ row_start, int BP) {
    __shared__ int es[ES_CAP];       // 20 KB
    __shared__ int rlen[BPMAX];
    __shared__ int rst[BPMAX];
    __shared__ int s[BPMAX];
    __shared__ int cnt[BUCKN];
    __shared__ int cur[BUCKN];
    __shared__ int ntot;
    const int t = threadIdx.x, buck = blockIdx.x;
    if (t < BPMAX) { rlen[t] = 0; rst[t] = 0; }
    __syncthreads();
    if (t < BP) {
        int a = hdr[t * HDRS + buck];
        int e = hdr[t * HDRS + buck + 1];
        rst[t] = min(max(a, 0), CHUNK);
        rlen[t] = min(max(e - a, 0), CHUNK);
    }
    __syncthreads();
    int v = (t < BPMAX) ? rlen[t] : 0;
    if (t < BPMAX) s[t] = v;
    __syncthreads();
    for (int off = 1; off < BPMAX; off <<= 1) {
        int u = (t >= off && t < BPMAX) ? s[t - off] : 0;
        __syncthreads();
        if (t < BPMAX) s[t] += u;
        __syncthreads();
    }
    if (t == BPMAX - 1) ntot = min(s[BPMAX - 1], ES_CAP);
    __syncthreads();
    const int n = ntot;
    if (t < BP) {
        const int off0 = s[t] - v;
        const int base = t * CHUNK + rst[t];
        for (int k = 0; k < rlen[t]; ++k) {
            int p = off0 + k;
            if (p < ES_CAP) es[p] = col[base + k];
        }
    }
    __syncthreads();
    if (t < BUCKN) cnt[t] = 0;
    __syncthreads();
    for (int i = t; i < n; i += 1024) atomicAdd(&cnt[(es[i] >> 17) & (BUCKN - 1)], 1);
    __syncthreads();
    if (t < BUCKN) cur[t] = cnt[t];
    __syncthreads();
    for (int off = 1; off < BUCKN; off <<= 1) {
        int u = (t < BUCKN && t >= off) ? cur[t - off] : 0;
        __syncthreads();
        if (t < BUCKN) cur[t] += u;
        __syncthreads();
    }
    if (t < BUCKN) {
        int excl = cur[t] - cnt[t];
        int node = buck * BUCKN + t;
        if (node < N) {
            deg[node] = cnt[t];
            row_start[node] = buck * STRIDE + excl;
        }
        cur[t] = excl;
    }
    __syncthreads();
    for (int i = t; i < n; i += 1024) {
        int p = es[i];
        int pos = atomicAdd(&cur[(p >> 17) & (BUCKN - 1)], 1);
        pos = min(max(pos, 0), STRIDE - 1);
        col2[buck * STRIDE + pos] = p & 0x1FFFF;
    }
}

// ---------------- layer 1 transform: g1h = fp16( dis * (x @ W1^T) ) ----------------
__global__ __launch_bounds__(256) void k_xw1(
        const float* __restrict__ x, const float* __restrict__ W1,
        const int* __restrict__ deg, __half* __restrict__ g1h) {
    __shared__ float4 wtv[32 * 33];   // [kb][j] quad of W1[j][4kb..4kb+3], pad 33
    __shared__ float4 xsv[1024];      // 32 nodes x 32 k-quads
    const int t = threadIdx.x;
    const float4* W1v = (const float4*)W1;
    for (int idx = t; idx < 1024; idx += 256) {
        int j = idx >> 5, kb = idx & 31;
        wtv[kb * 33 + j] = W1v[idx];
    }
    const float4* x4 = (const float4*)x + (size_t)blockIdx.x * 1024;
    for (int idx = t; idx < 1024; idx += 256) xsv[idx] = x4[idx];
    __syncthreads();

    const int j = t & 31, ng = t >> 5;
    float a0 = 0.f, a1 = 0.f, a2 = 0.f, a3 = 0.f;
#pragma unroll 4
    for (int kb = 0; kb < 32; ++kb) {
        float4 w = wtv[kb * 33 + j];
        float4 x0 = xsv[(4 * ng + 0) * 32 + kb];
        float4 x1 = xsv[(4 * ng + 1) * 32 + kb];
        float4 x2 = xsv[(4 * ng + 2) * 32 + kb];
        float4 x3 = xsv[(4 * ng + 3) * 32 + kb];
        a0 = fmaf(w.x, x0.x, fmaf(w.y, x0.y, fmaf(w.z, x0.z, fmaf(w.w, x0.w, a0))));
        a1 = fmaf(w.x, x1.x, fmaf(w.y, x1.y, fmaf(w.z, x1.z, fmaf(w.w, x1.w, a1))));
        a2 = fmaf(w.x, x2.x, fmaf(w.y, x2.y, fmaf(w.z, x2.z, fmaf(w.w, x2.w, a2))));
        a3 = fmaf(w.x, x3.x, fmaf(w.y, x3.y, fmaf(w.z, x3.z, fmaf(w.w, x3.w, a3))));
    }
    const int nb = blockIdx.x * 32 + 4 * ng;
    g1h[(nb + 0) * 32 + j] = __float2half(a0 * rsqrtf((float)(deg[nb + 0] + 1)));
    g1h[(nb + 1) * 32 + j] = __float2half(a1 * rsqrtf((float)(deg[nb + 1] + 1)));
    g1h[(nb + 2) * 32 + j] = __float2half(a2 * rsqrtf((float)(deg[nb + 2] + 1)));
    g1h[(nb + 3) * 32 + j] = __float2half(a3 * rsqrtf((float)(deg[nb + 3] + 1)));
}

// ---------------- gather layer 1 + FUSED layer-2 transform (lean tail) ----------------
__global__ __launch_bounds__(256) void k_gather1(
        const int* __restrict__ row_start, const int* __restrict__ deg,
        const int* __restrict__ col2, const __half* __restrict__ g1h,
        const float* __restrict__ b1, const float* __restrict__ W2,
        __half* __restrict__ g2h) {
    __shared__ float h1s[64 * 33];   // 8.4 KB, pad 33
    __shared__ float w2t[32 * 17];   // W2 transposed [k][j], pad 17
    const int t = threadIdx.x;
    for (int idx = t; idx < 512; idx += 256) {
        int j = idx >> 5, k = idx & 31;
        w2t[k * 17 + j] = W2[idx];
    }
    const int lane = t & 63, w = t >> 6;
    const int q = lane & 3;                      // feature octet
    const int nloc = w * 16 + (lane >> 2);
    const int node = blockIdx.x * 64 + nloc;
    const int nc = node < N ? node : N - 1;
    const int rs = row_start[nc];
    const int ne = (node < N) ? deg[nc] : 0;
    const uint4* g1v = (const uint4*)g1h;

    float acc[8];
    {
        uint4 rv = g1v[nc * 4 + q];
        const __half2* hp = (const __half2*)&rv;
#pragma unroll
        for (int m2 = 0; m2 < 4; ++m2) {
            float2 f = __half22float2(hp[m2]);
            acc[2 * m2] = f.x;
            acc[2 * m2 + 1] = f.y;
        }
    }
    for (int base = 0; base < ne; base += 16) {
        int sv[4];
#pragma unroll
        for (int c = 0; c < 4; ++c)
            sv[c] = (base + 4 * c + q < ne) ? col2[rs + base + 4 * c + q] : 0;
        int idx[16];
#pragma unroll
        for (int c = 0; c < 4; ++c)
#pragma unroll
            for (int u = 0; u < 4; ++u)
                idx[4 * c + u] = min(__shfl(sv[c], u, 4), N - 1);
        uint4 rv[16];
#pragma unroll
        for (int u = 0; u < 16; ++u) rv[u] = g1v[idx[u] * 4 + q];
#pragma unroll
        for (int u = 0; u < 16; ++u) {
            float wt = (base + u < ne) ? 1.f : 0.f;
            const __half2* hp = (const __half2*)&rv[u];
#pragma unroll
            for (int m2 = 0; m2 < 4; ++m2) {
                float2 f = __half22float2(hp[m2]);
                acc[2 * m2]     = fmaf(wt, f.x, acc[2 * m2]);
                acc[2 * m2 + 1] = fmaf(wt, f.y, acc[2 * m2 + 1]);
            }
        }
    }
    {
        const float dis = rsqrtf((float)(ne + 1));
#pragma unroll
        for (int u = 0; u < 8; ++u) {
            float v = (node < N) ? (acc[u] * dis + b1[q * 8 + u]) : 0.f;
            h1s[nloc * 33 + q * 8 + u] = v > 0.f ? v : 0.f;
        }
    }
    __syncthreads();
    const int n2 = t >> 2, jq = (t & 3) * 4;
    const int node2 = blockIdx.x * 64 + n2;
    if (node2 < N) {
        float a0 = 0.f, a1 = 0.f, a2 = 0.f, a3 = 0.f;
        const float* hr = h1s + n2 * 33;
#pragma unroll
        for (int k = 0; k < 32; ++k) {
            float h = hr[k];
            a0 = fmaf(h, w2t[k * 17 + jq + 0], a0);
            a1 = fmaf(h, w2t[k * 17 + jq + 1], a1);
            a2 = fmaf(h, w2t[k * 17 + jq + 2], a2);
            a3 = fmaf(h, w2t[k * 17 + jq + 3], a3);
        }
        const float dis2 = rsqrtf((float)(deg[node2] + 1));
        __half2* g2p = (__half2*)(g2h + node2 * 16 + jq);
        g2p[0] = __floats2half2_rn(a0 * dis2, a1 * dis2);
        g2p[1] = __floats2half2_rn(a2 * dis2, a3 * dis2);
    }
}

// ---------------- gather layer 2 (lean; LSTM kept separate for occupancy) ----------------
__global__ __launch_bounds__(256) void k_gather2(
        const int* __restrict__ row_start, const int* __restrict__ deg,
        const int* __restrict__ col2, const __half* __restrict__ g2h,
        const float* __restrict__ b2, float* __restrict__ h2) {
    const int t = threadIdx.x;
    const int lane = t & 63, w = t >> 6;
    const int q = lane & 1;
    const int node = blockIdx.x * 128 + w * 32 + (lane >> 1);
    const int nc = node < N ? node : N - 1;
    const int rs = row_start[nc];
    const int ne = (node < N) ? deg[nc] : 0;
    const uint4* g2v = (const uint4*)g2h;

    float acc[8];
    {
        uint4 rv = g2v[nc * 2 + q];
        const __half2* hp = (const __half2*)&rv;
#pragma unroll
        for (int m2 = 0; m2 < 4; ++m2) {
            float2 f = __half22float2(hp[m2]);
            acc[2 * m2] = f.x;
            acc[2 * m2 + 1] = f.y;
        }
    }
    for (int base = 0; base < ne; base += 16) {
        int sv[8];
#pragma unroll
        for (int c = 0; c < 8; ++c)
            sv[c] = (base + 2 * c + q < ne) ? col2[rs + base + 2 * c + q] : 0;
        int idx[16];
#pragma unroll
        for (int c = 0; c < 8; ++c) {
            idx[2 * c]     = min(__shfl(sv[c], 0, 2), N - 1);
            idx[2 * c + 1] = min(__shfl(sv[c], 1, 2), N - 1);
        }
        uint4 rv[16];
#pragma unroll
        for (int u = 0; u < 16; ++u) rv[u] = g2v[idx[u] * 2 + q];
#pragma unroll
        for (int u = 0; u < 16; ++u) {
            float wt = (base + u < ne) ? 1.f : 0.f;
            const __half2* hp = (const __half2*)&rv[u];
#pragma unroll
            for (int m2 = 0; m2 < 4; ++m2) {
                float2 f = __half22float2(hp[m2]);
                acc[2 * m2]     = fmaf(wt, f.x, acc[2 * m2]);
                acc[2 * m2 + 1] = fmaf(wt, f.y, acc[2 * m2 + 1]);
            }
        }
    }
    if (node < N) {
        const float dis = rsqrtf((float)(ne + 1));
        float4* h2v = (float4*)h2;
#pragma unroll
        for (int h = 0; h < 2; ++h) {
            float4 o;
            float v0 = acc[4 * h + 0] * dis + b2[q * 8 + 4 * h + 0];
            float v1 = acc[4 * h + 1] * dis + b2[q * 8 + 4 * h + 1];
            float v2 = acc[4 * h + 2] * dis + b2[q * 8 + 4 * h + 2];
            float v3 = acc[4 * h + 3] * dis + b2[q * 8 + 4 * h + 3];
            o.x = v0 > 0.f ? v0 : 0.f;
            o.y = v1 > 0.f ? v1 : 0.f;
            o.z = v2 > 0.f ? v2 : 0.f;
            o.w = v3 > 0.f ? v3 : 0.f;
            h2v[node * 4 + q * 2 + h] = o;
        }
    }
}

// ---------------- LSTM (h0=c0=0) + output head ----------------
__global__ __launch_bounds__(256) void k_final(
        const float* __restrict__ h2g,
        const float* __restrict__ w_ih, const float* __restrict__ b_ih,
        const float* __restrict__ b_hh, const float* __restrict__ W_out,
        const float* __restrict__ b_out, float* __restrict__ out) {
    __shared__ float wih[512];
    __shared__ float bias[32];
    __shared__ float wout[8];
    __shared__ float bo;
    const int t = threadIdx.x;
    for (int idx = t; idx < 512; idx += 256) wih[idx] = w_ih[idx];
    if (t < 32) bias[t] = b_ih[t] + b_hh[t];
    if (t < 8)  wout[t] = W_out[t];
    if (t == 0) bo = b_out[0];
    __syncthreads();

    const int i = blockIdx.x * 256 + t;
    if (i >= N) return;
    float h2[16];
    const float4* a4 = (const float4*)(h2g + (size_t)i * 16);
#pragma unroll
    for (int q = 0; q < 4; ++q) {
        float4 v = a4[q];
        h2[q * 4 + 0] = v.x; h2[q * 4 + 1] = v.y;
        h2[q * 4 + 2] = v.z; h2[q * 4 + 3] = v.w;
    }
    float oacc = 0.f;
#pragma unroll
    for (int q = 0; q < 8; ++q) {
        float gi = bias[q], gg = bias[16 + q], go = bias[24 + q];
#pragma unroll
        for (int k = 0; k < 16; ++k) {
            gi = fmaf(h2[k], wih[q * 16 + k], gi);
            gg = fmaf(h2[k], wih[(16 + q) * 16 + k], gg);
            go = fmaf(h2[k], wih[(24 + q) * 16 + k], go);
        }
        float c  = (1.f / (1.f + expf(-gi))) * tanhf(gg);
        float hh = (1.f / (1.f + expf(-go))) * tanhf(c);
        oacc = fmaf(hh, wout[q], oacc);
    }
    out[i] = oacc + bo;
}

extern "C" void kernel_launch(void* const* d_in, const int* in_sizes, int n_in,
                              void* d_out, int out_size, void* d_ws, size_t ws_size,
                              hipStream_t stream) {
    const float* x     = (const float*)d_in[0];
    const int*   ei    = (const int*)d_in[1];
    const float* W1    = (const float*)d_in[2];
    const float* b1    = (const float*)d_in[3];
    const float* W2    = (const float*)d_in[4];
    const float* b2    = (const float*)d_in[5];
    const float* w_ih  = (const float*)d_in[6];
    // d_in[7] = w_hh: unused (h0 = 0)
    const float* b_ih  = (const float*)d_in[8];
    const float* b_hh  = (const float*)d_in[9];
    const float* W_out = (const float*)d_in[10];
    const float* b_out = (const float*)d_in[11];
    float* out = (float*)d_out;

    const int E = in_sizes[1] / 2;
    const int* src = ei;
    const int* dst = ei + E;
    const int BP = (E + CHUNK - 1) / CHUNK;   // 391 <= BPMAX

    // workspace (4 B units); disjoint regions; base offsets stay 16 B aligned
    int* col       = (int*)d_ws;                        // BPMAX*CHUNK
    int* hdr       = col + (size_t)BPMAX * CHUNK;       // BPMAX*HDRS (400,896)
    int* col2      = hdr + (size_t)BPMAX * HDRS;        // COLCAP
    int* deg       = col2 + COLCAP;                     // N
    int* row_start = deg + N;                           // N
    int* base2     = row_start + N;
    __half* g1h    = (__half*)base2;                      // N*32 halves = N*16 ints
    __half* g2h    = (__half*)(base2 + (size_t)N * 16);   // N*16 halves = N*8 ints
    float* h2      = (float*)(base2 + (size_t)N * 24);    // N*16 floats

    k_part   <<<BP,              1024, 0, stream>>>(src, dst, col, hdr, E);
    k_sort   <<<NBUCK,           1024, 0, stream>>>(col, hdr, col2, deg, row_start, BP);
    k_xw1    <<<N / 32,          256,  0, stream>>>(x, W1, deg, g1h);
    k_gather1<<<(N + 63) / 64,   256,  0, stream>>>(row_start, deg, col2, g1h, b1, W2, g2h);
    k_gather2<<<(N + 127) / 128, 256,  0, stream>>>(row_start, deg, col2, g2h, b2, h2);
    k_final  <<<(N + 255) / 256, 256,  0, stream>>>(h2, w_ih, b_ih, b_hh, W_out, b_out, out);
}

// Round 15
// 253.687 us; speedup vs baseline: 1.0315x; 1.0315x over previous
//
#include <hip/hip_runtime.h>
#include <hip/hip_fp16.h>
#include <math.h>

static constexpr int N = 100000;
static constexpr int SHIFT = 7;                        // 128 nodes / bucket
static constexpr int BUCKN = 1 << SHIFT;               // 128
static constexpr int NBUCK = (N + BUCKN - 1) >> SHIFT; // 782
static constexpr int HDRS  = NBUCK + 1;                // 783 offsets per block
static constexpr int CHUNK = 8192;                     // edges per partition block
static constexpr int BPMAX = 512;                      // max partition blocks supported
static constexpr int STRIDE = 5120;                    // per-bucket CSR capacity (16 sigma)
static constexpr int COLCAP = NBUCK * STRIDE;
static constexpr int ES_CAP = STRIDE;

// ---------------- partition: per-block LDS counting sort, COALESCED writes ----------------
__global__ __launch_bounds__(1024) void k_part(const int* __restrict__ src,
                                               const int* __restrict__ dst,
                                               int* __restrict__ col,
                                               int* __restrict__ hdr, int E) {
    __shared__ int stage[CHUNK];     // 32 KB
    __shared__ int hl[NBUCK];
    __shared__ int cur[NBUCK];
    __shared__ int s[1024];
    const int t = threadIdx.x, b = blockIdx.x;
    if (t < NBUCK) hl[t] = 0;        // 1024 >= NBUCK: single-shot OK
    __syncthreads();
    const int e0 = b * CHUNK;
    const int m = min(CHUNK, E - e0);
    for (int i = t; i < m; i += 1024) atomicAdd(&hl[dst[e0 + i] >> SHIFT], 1);
    __syncthreads();
    int v = (t < NBUCK) ? hl[t] : 0;
    s[t] = v;
    __syncthreads();
    for (int off = 1; off < 1024; off <<= 1) {
        int u = (t >= off) ? s[t - off] : 0;
        __syncthreads();
        s[t] += u;
        __syncthreads();
    }
    if (t < NBUCK) {
        int excl = s[t] - v;
        cur[t] = excl;
        hdr[b * HDRS + t] = excl;
    }
    if (t == 0) hdr[b * HDRS + NBUCK] = m;
    __syncthreads();
    for (int i = t; i < m; i += 1024) {
        int d = dst[e0 + i];
        int pos = atomicAdd(&cur[d >> SHIFT], 1);
        pos = min(max(pos, 0), CHUNK - 1);               // safety clamp (no-op)
        stage[pos] = (src[e0 + i] & 0x1FFFF) | ((d & (BUCKN - 1)) << 17);
    }
    __syncthreads();
    for (int i = t; i < m; i += 1024) col[e0 + i] = stage[i];   // sequential
}

// ---------------- per-bucket: gather runs (16-lane groups), sort -> CSR in col2 ----------------
__global__ __launch_bounds__(1024) void k_sort(const int* __restrict__ col,
                                               const int* __restrict__ hdr,
                                               int* __restrict__ col2,
                                               int* __restrict__ deg,
                                               int* __restrict__ row_start, int BP) {
    __shared__ int es[ES_CAP];       // 20 KB
    __shared__ int rlen[BPMAX];
    __shared__ int rst[BPMAX];
    __shared__ int roff[BPMAX];
    __shared__ int s[BPMAX];
    __shared__ int cnt[BUCKN];
    __shared__ int cur[BUCKN];
    __shared__ int ntot;
    const int t = threadIdx.x, buck = blockIdx.x;
    if (t < BPMAX) { rlen[t] = 0; rst[t] = 0; }
    __syncthreads();
    if (t < BP) {
        int a = hdr[t * HDRS + buck];
        int e = hdr[t * HDRS + buck + 1];
        rst[t] = min(max(a, 0), CHUNK);
        rlen[t] = min(max(e - a, 0), CHUNK);
    }
    __syncthreads();
    int v = (t < BPMAX) ? rlen[t] : 0;
    if (t < BPMAX) s[t] = v;
    __syncthreads();
    for (int off = 1; off < BPMAX; off <<= 1) {
        int u = (t >= off && t < BPMAX) ? s[t - off] : 0;
        __syncthreads();
        if (t < BPMAX) s[t] += u;
        __syncthreads();
    }
    if (t < BPMAX) roff[t] = s[t] - v;
    if (t == BPMAX - 1) ntot = min(s[BPMAX - 1], ES_CAP);
    __syncthreads();
    const int n = ntot;
    // cooperative run copy: 64 groups x 16 lanes (round-14 did 1 thread/run serially)
    {
        const int g = t >> 4, l = t & 15;
        for (int r = g; r < BP; r += 64) {
            const int len = rlen[r];
            const int base = r * CHUNK + rst[r];
            const int o = roff[r];
            for (int k = l; k < len; k += 16) {
                int p = o + k;
                if (p < ES_CAP) es[p] = col[base + k];
            }
        }
    }
    __syncthreads();
    if (t < BUCKN) cnt[t] = 0;
    __syncthreads();
    for (int i = t; i < n; i += 1024) atomicAdd(&cnt[(es[i] >> 17) & (BUCKN - 1)], 1);
    __syncthreads();
    if (t < BUCKN) cur[t] = cnt[t];
    __syncthreads();
    for (int off = 1; off < BUCKN; off <<= 1) {
        int u = (t < BUCKN && t >= off) ? cur[t - off] : 0;
        __syncthreads();
        if (t < BUCKN) cur[t] += u;
        __syncthreads();
    }
    if (t < BUCKN) {
        int excl = cur[t] - cnt[t];
        int node = buck * BUCKN + t;
        if (node < N) {
            deg[node] = cnt[t];
            row_start[node] = buck * STRIDE + excl;
        }
        cur[t] = excl;
    }
    __syncthreads();
    for (int i = t; i < n; i += 1024) {
        int p = es[i];
        int pos = atomicAdd(&cur[(p >> 17) & (BUCKN - 1)], 1);
        pos = min(max(pos, 0), STRIDE - 1);
        col2[buck * STRIDE + pos] = p & 0x1FFFF;
    }
}

// ---------------- layer 1 transform: g1h = fp16( dis * (x @ W1^T) ) ----------------
__global__ __launch_bounds__(256) void k_xw1(
        const float* __restrict__ x, const float* __restrict__ W1,
        const int* __restrict__ deg, __half* __restrict__ g1h) {
    __shared__ float4 wtv[32 * 33];   // [kb][j] quad of W1[j][4kb..4kb+3], pad 33
    __shared__ float4 xsv[1024];      // 32 nodes x 32 k-quads
    const int t = threadIdx.x;
    const float4* W1v = (const float4*)W1;
    for (int idx = t; idx < 1024; idx += 256) {
        int j = idx >> 5, kb = idx & 31;
        wtv[kb * 33 + j] = W1v[idx];
    }
    const float4* x4 = (const float4*)x + (size_t)blockIdx.x * 1024;
    for (int idx = t; idx < 1024; idx += 256) xsv[idx] = x4[idx];
    __syncthreads();

    const int j = t & 31, ng = t >> 5;
    float a0 = 0.f, a1 = 0.f, a2 = 0.f, a3 = 0.f;
#pragma unroll 4
    for (int kb = 0; kb < 32; ++kb) {
        float4 w = wtv[kb * 33 + j];
        float4 x0 = xsv[(4 * ng + 0) * 32 + kb];
        float4 x1 = xsv[(4 * ng + 1) * 32 + kb];
        float4 x2 = xsv[(4 * ng + 2) * 32 + kb];
        float4 x3 = xsv[(4 * ng + 3) * 32 + kb];
        a0 = fmaf(w.x, x0.x, fmaf(w.y, x0.y, fmaf(w.z, x0.z, fmaf(w.w, x0.w, a0))));
        a1 = fmaf(w.x, x1.x, fmaf(w.y, x1.y, fmaf(w.z, x1.z, fmaf(w.w, x1.w, a1))));
        a2 = fmaf(w.x, x2.x, fmaf(w.y, x2.y, fmaf(w.z, x2.z, fmaf(w.w, x2.w, a2))));
        a3 = fmaf(w.x, x3.x, fmaf(w.y, x3.y, fmaf(w.z, x3.z, fmaf(w.w, x3.w, a3))));
    }
    const int nb = blockIdx.x * 32 + 4 * ng;
    g1h[(nb + 0) * 32 + j] = __float2half(a0 * rsqrtf((float)(deg[nb + 0] + 1)));
    g1h[(nb + 1) * 32 + j] = __float2half(a1 * rsqrtf((float)(deg[nb + 1] + 1)));
    g1h[(nb + 2) * 32 + j] = __float2half(a2 * rsqrtf((float)(deg[nb + 2] + 1)));
    g1h[(nb + 3) * 32 + j] = __float2half(a3 * rsqrtf((float)(deg[nb + 3] + 1)));
}

// ---------------- gather layer 1 + FUSED layer-2 transform (lean tail) ----------------
__global__ __launch_bounds__(256) void k_gather1(
        const int* __restrict__ row_start, const int* __restrict__ deg,
        const int* __restrict__ col2, const __half* __restrict__ g1h,
        const float* __restrict__ b1, const float* __restrict__ W2,
        __half* __restrict__ g2h) {
    __shared__ float h1s[64 * 33];   // 8.4 KB, pad 33
    __shared__ float w2t[32 * 17];   // W2 transposed [k][j], pad 17
    const int t = threadIdx.x;
    for (int idx = t; idx < 512; idx += 256) {
        int j = idx >> 5, k = idx & 31;
        w2t[k * 17 + j] = W2[idx];
    }
    const int lane = t & 63, w = t >> 6;
    const int q = lane & 3;                      // feature octet
    const int nloc = w * 16 + (lane >> 2);
    const int node = blockIdx.x * 64 + nloc;
    const int nc = node < N ? node : N - 1;
    const int rs = row_start[nc];
    const int ne = (node < N) ? deg[nc] : 0;
    const uint4* g1v = (const uint4*)g1h;

    float acc[8];
    {
        uint4 rv = g1v[nc * 4 + q];
        const __half2* hp = (const __half2*)&rv;
#pragma unroll
        for (int m2 = 0; m2 < 4; ++m2) {
            float2 f = __half22float2(hp[m2]);
            acc[2 * m2] = f.x;
            acc[2 * m2 + 1] = f.y;
        }
    }
    for (int base = 0; base < ne; base += 16) {
        int sv[4];
#pragma unroll
        for (int c = 0; c < 4; ++c)
            sv[c] = (base + 4 * c + q < ne) ? col2[rs + base + 4 * c + q] : 0;
        int idx[16];
#pragma unroll
        for (int c = 0; c < 4; ++c)
#pragma unroll
            for (int u = 0; u < 4; ++u)
                idx[4 * c + u] = min(__shfl(sv[c], u, 4), N - 1);
        uint4 rv[16];
#pragma unroll
        for (int u = 0; u < 16; ++u) rv[u] = g1v[idx[u] * 4 + q];
#pragma unroll
        for (int u = 0; u < 16; ++u) {
            float wt = (base + u < ne) ? 1.f : 0.f;
            const __half2* hp = (const __half2*)&rv[u];
#pragma unroll
            for (int m2 = 0; m2 < 4; ++m2) {
                float2 f = __half22float2(hp[m2]);
                acc[2 * m2]     = fmaf(wt, f.x, acc[2 * m2]);
                acc[2 * m2 + 1] = fmaf(wt, f.y, acc[2 * m2 + 1]);
            }
        }
    }
    {
        const float dis = rsqrtf((float)(ne + 1));
#pragma unroll
        for (int u = 0; u < 8; ++u) {
            float v = (node < N) ? (acc[u] * dis + b1[q * 8 + u]) : 0.f;
            h1s[nloc * 33 + q * 8 + u] = v > 0.f ? v : 0.f;
        }
    }
    __syncthreads();
    const int n2 = t >> 2, jq = (t & 3) * 4;
    const int node2 = blockIdx.x * 64 + n2;
    if (node2 < N) {
        float a0 = 0.f, a1 = 0.f, a2 = 0.f, a3 = 0.f;
        const float* hr = h1s + n2 * 33;
#pragma unroll
        for (int k = 0; k < 32; ++k) {
            float h = hr[k];
            a0 = fmaf(h, w2t[k * 17 + jq + 0], a0);
            a1 = fmaf(h, w2t[k * 17 + jq + 1], a1);
            a2 = fmaf(h, w2t[k * 17 + jq + 2], a2);
            a3 = fmaf(h, w2t[k * 17 + jq + 3], a3);
        }
        const float dis2 = rsqrtf((float)(deg[node2] + 1));
        __half2* g2p = (__half2*)(g2h + node2 * 16 + jq);
        g2p[0] = __floats2half2_rn(a0 * dis2, a1 * dis2);
        g2p[1] = __floats2half2_rn(a2 * dis2, a3 * dis2);
    }
}

// ---------------- gather layer 2 (lean; LSTM kept separate for occupancy) ----------------
__global__ __launch_bounds__(256) void k_gather2(
        const int* __restrict__ row_start, const int* __restrict__ deg,
        const int* __restrict__ col2, const __half* __restrict__ g2h,
        const float* __restrict__ b2, float* __restrict__ h2) {
    const int t = threadIdx.x;
    const int lane = t & 63, w = t >> 6;
    const int q = lane & 1;
    const int node = blockIdx.x * 128 + w * 32 + (lane >> 1);
    const int nc = node < N ? node : N - 1;
    const int rs = row_start[nc];
    const int ne = (node < N) ? deg[nc] : 0;
    const uint4* g2v = (const uint4*)g2h;

    float acc[8];
    {
        uint4 rv = g2v[nc * 2 + q];
        const __half2* hp = (const __half2*)&rv;
#pragma unroll
        for (int m2 = 0; m2 < 4; ++m2) {
            float2 f = __half22float2(hp[m2]);
            acc[2 * m2] = f.x;
            acc[2 * m2 + 1] = f.y;
        }
    }
    for (int base = 0; base < ne; base += 16) {
        int sv[8];
#pragma unroll
        for (int c = 0; c < 8; ++c)
            sv[c] = (base + 2 * c + q < ne) ? col2[rs + base + 2 * c + q] : 0;
        int idx[16];
#pragma unroll
        for (int c = 0; c < 8; ++c) {
            idx[2 * c]     = min(__shfl(sv[c], 0, 2), N - 1);
            idx[2 * c + 1] = min(__shfl(sv[c], 1, 2), N - 1);
        }
        uint4 rv[16];
#pragma unroll
        for (int u = 0; u < 16; ++u) rv[u] = g2v[idx[u] * 2 + q];
#pragma unroll
        for (int u = 0; u < 16; ++u) {
            float wt = (base + u < ne) ? 1.f : 0.f;
            const __half2* hp = (const __half2*)&rv[u];
#pragma unroll
            for (int m2 = 0; m2 < 4; ++m2) {
                float2 f = __half22float2(hp[m2]);
                acc[2 * m2]     = fmaf(wt, f.x, acc[2 * m2]);
                acc[2 * m2 + 1] = fmaf(wt, f.y, acc[2 * m2 + 1]);
            }
        }
    }
    if (node < N) {
        const float dis = rsqrtf((float)(ne + 1));
        float4* h2v = (float4*)h2;
#pragma unroll
        for (int h = 0; h < 2; ++h) {
            float4 o;
            float v0 = acc[4 * h + 0] * dis + b2[q * 8 + 4 * h + 0];
            float v1 = acc[4 * h + 1] * dis + b2[q * 8 + 4 * h + 1];
            float v2 = acc[4 * h + 2] * dis + b2[q * 8 + 4 * h + 2];
            float v3 = acc[4 * h + 3] * dis + b2[q * 8 + 4 * h + 3];
            o.x = v0 > 0.f ? v0 : 0.f;
            o.y = v1 > 0.f ? v1 : 0.f;
            o.z = v2 > 0.f ? v2 : 0.f;
            o.w = v3 > 0.f ? v3 : 0.f;
            h2v[node * 4 + q * 2 + h] = o;
        }
    }
}

// ---------------- LSTM (h0=c0=0) + output head ----------------
__global__ __launch_bounds__(256) void k_final(
        const float* __restrict__ h2g,
        const float* __restrict__ w_ih, const float* __restrict__ b_ih,
        const float* __restrict__ b_hh, const float* __restrict__ W_out,
        const float* __restrict__ b_out, float* __restrict__ out) {
    __shared__ float wih[512];
    __shared__ float bias[32];
    __shared__ float wout[8];
    __shared__ float bo;
    const int t = threadIdx.x;
    for (int idx = t; idx < 512; idx += 256) wih[idx] = w_ih[idx];
    if (t < 32) bias[t] = b_ih[t] + b_hh[t];
    if (t < 8)  wout[t] = W_out[t];
    if (t == 0) bo = b_out[0];
    __syncthreads();

    const int i = blockIdx.x * 256 + t;
    if (i >= N) return;
    float h2[16];
    const float4* a4 = (const float4*)(h2g + (size_t)i * 16);
#pragma unroll
    for (int q = 0; q < 4; ++q) {
        float4 v = a4[q];
        h2[q * 4 + 0] = v.x; h2[q * 4 + 1] = v.y;
        h2[q * 4 + 2] = v.z; h2[q * 4 + 3] = v.w;
    }
    float oacc = 0.f;
#pragma unroll
    for (int q = 0; q < 8; ++q) {
        float gi = bias[q], gg = bias[16 + q], go = bias[24 + q];
#pragma unroll
        for (int k = 0; k < 16; ++k) {
            gi = fmaf(h2[k], wih[q * 16 + k], gi);
            gg = fmaf(h2[k], wih[(16 + q) * 16 + k], gg);
            go = fmaf(h2[k], wih[(24 + q) * 16 + k], go);
        }
        float c  = (1.f / (1.f + expf(-gi))) * tanhf(gg);
        float hh = (1.f / (1.f + expf(-go))) * tanhf(c);
        oacc = fmaf(hh, wout[q], oacc);
    }
    out[i] = oacc + bo;
}

extern "C" void kernel_launch(void* const* d_in, const int* in_sizes, int n_in,
                              void* d_out, int out_size, void* d_ws, size_t ws_size,
                              hipStream_t stream) {
    const float* x     = (const float*)d_in[0];
    const int*   ei    = (const int*)d_in[1];
    const float* W1    = (const float*)d_in[2];
    const float* b1    = (const float*)d_in[3];
    const float* W2    = (const float*)d_in[4];
    const float* b2    = (const float*)d_in[5];
    const float* w_ih  = (const float*)d_in[6];
    // d_in[7] = w_hh: unused (h0 = 0)
    const float* b_ih  = (const float*)d_in[8];
    const float* b_hh  = (const float*)d_in[9];
    const float* W_out = (const float*)d_in[10];
    const float* b_out = (const float*)d_in[11];
    float* out = (float*)d_out;

    const int E = in_sizes[1] / 2;
    const int* src = ei;
    const int* dst = ei + E;
    int BP = (E + CHUNK - 1) / CHUNK;   // 391
    if (BP > BPMAX) BP = BPMAX;

    // workspace (4 B units); disjoint regions; base offsets stay 16 B aligned
    int* col       = (int*)d_ws;                        // BPMAX*CHUNK
    int* hdr       = col + (size_t)BPMAX * CHUNK;       // BPMAX*HDRS
    int* col2      = hdr + (size_t)BPMAX * HDRS;        // COLCAP
    int* deg       = col2 + COLCAP;                     // N
    int* row_start = deg + N;                           // N
    int* base2     = row_start + N;
    __half* g1h    = (__half*)base2;                      // N*32 halves = N*16 ints
    __half* g2h    = (__half*)(base2 + (size_t)N * 16);   // N*16 halves = N*8 ints
    float* h2      = (float*)(base2 + (size_t)N * 24);    // N*16 floats

    k_part   <<<BP,              1024, 0, stream>>>(src, dst, col, hdr, E);
    k_sort   <<<NBUCK,           1024, 0, stream>>>(col, hdr, col2, deg, row_start, BP);
    k_xw1    <<<N / 32,          256,  0, stream>>>(x, W1, deg, g1h);
    k_gather1<<<(N + 63) / 64,   256,  0, stream>>>(row_start, deg, col2, g1h, b1, W2, g2h);
    k_gather2<<<(N + 127) / 128, 256,  0, stream>>>(row_start, deg, col2, g2h, b2, h2);
    k_final  <<<(N + 255) / 256, 256,  0, stream>>>(h2, w_ih, b_ih, b_hh, W_out, b_out, out);
}

// Round 16
// 246.074 us; speedup vs baseline: 1.0634x; 1.0309x over previous
//
#include <hip/hip_runtime.h>
#include <hip/hip_fp16.h>
#include <math.h>

static constexpr int N = 100000;
static constexpr int SHIFT = 7;                        // 128 nodes / bucket
static constexpr int BUCKN = 1 << SHIFT;               // 128
static constexpr int NBUCK = (N + BUCKN - 1) >> SHIFT; // 782
static constexpr int HDRS  = NBUCK + 1;                // 783 offsets per block
static constexpr int CHUNK = 8192;                     // edges per partition block
static constexpr int BPMAX = 512;                      // max partition blocks supported
static constexpr int STRIDE = 5120;                    // per-bucket CSR capacity (16 sigma)
static constexpr int COLCAP = NBUCK * STRIDE;
static constexpr int ES_CAP = STRIDE;

// inclusive block scan over 1024 threads via wave shuffles (2 barriers + 1 guard)
__device__ __forceinline__ int block_scan_incl(int v, int* wtot, int t) {
    const int lane = t & 63, wv = t >> 6;
    int x = v;
#pragma unroll
    for (int o = 1; o < 64; o <<= 1) {
        int y = __shfl_up(x, o, 64);
        if (lane >= o) x += y;
    }
    __syncthreads();                 // protect wtot reuse across calls
    if (lane == 63) wtot[wv] = x;
    __syncthreads();
    if (t < 16) {
        int y = wtot[t];
#pragma unroll
        for (int o = 1; o < 16; o <<= 1) {
            int z = __shfl_up(y, o, 16);
            if (t >= o) y += z;
        }
        wtot[t] = y;
    }
    __syncthreads();
    return x + (wv ? wtot[wv - 1] : 0);
}

// ---------------- partition: per-block LDS counting sort, COALESCED writes ----------------
__global__ __launch_bounds__(1024) void k_part(const int* __restrict__ src,
                                               const int* __restrict__ dst,
                                               int* __restrict__ col,
                                               int* __restrict__ hdr, int E) {
    __shared__ int stage[CHUNK];     // 32 KB
    __shared__ int hl[NBUCK];
    __shared__ int cur[NBUCK];
    __shared__ int wtot[16];
    const int t = threadIdx.x, b = blockIdx.x;
    if (t < NBUCK) hl[t] = 0;        // 1024 >= NBUCK: single-shot OK
    __syncthreads();
    const int e0 = b * CHUNK;
    const int m = min(CHUNK, E - e0);
    for (int i = t; i < m; i += 1024) atomicAdd(&hl[dst[e0 + i] >> SHIFT], 1);
    __syncthreads();
    const int v = (t < NBUCK) ? hl[t] : 0;
    const int inc = block_scan_incl(v, wtot, t);
    if (t < NBUCK) {
        int excl = inc - v;
        cur[t] = excl;
        hdr[b * HDRS + t] = excl;
    }
    if (t == 0) hdr[b * HDRS + NBUCK] = m;
    __syncthreads();
    for (int i = t; i < m; i += 1024) {
        int d = dst[e0 + i];
        int pos = atomicAdd(&cur[d >> SHIFT], 1);
        pos = min(max(pos, 0), CHUNK - 1);               // safety clamp (no-op)
        stage[pos] = (src[e0 + i] & 0x1FFFF) | ((d & (BUCKN - 1)) << 17);
    }
    __syncthreads();
    for (int i = t; i < m; i += 1024) col[e0 + i] = stage[i];   // sequential
}

// ---------------- per-bucket: gather runs (16-lane groups), sort -> CSR in col2 ----------------
__global__ __launch_bounds__(1024) void k_sort(const int* __restrict__ col,
                                               const int* __restrict__ hdr,
                                               int* __restrict__ col2,
                                               int* __restrict__ deg,
                                               int* __restrict__ row_start, int BP) {
    __shared__ int es[ES_CAP];       // 20 KB
    __shared__ int rlen[BPMAX];
    __shared__ int rst[BPMAX];
    __shared__ int roff[BPMAX];
    __shared__ int cnt[BUCKN];
    __shared__ int cur[BUCKN];
    __shared__ int wtot[16];
    __shared__ int ntot;
    const int t = threadIdx.x, buck = blockIdx.x;
    if (t < BPMAX) { rlen[t] = 0; rst[t] = 0; }
    __syncthreads();
    if (t < BP) {
        int a = hdr[t * HDRS + buck];
        int e = hdr[t * HDRS + buck + 1];
        rst[t] = min(max(a, 0), CHUNK);
        rlen[t] = min(max(e - a, 0), CHUNK);
    }
    __syncthreads();
    {
        const int v = (t < BPMAX) ? rlen[t] : 0;
        const int inc = block_scan_incl(v, wtot, t);
        if (t < BPMAX) roff[t] = inc - v;
        if (t == 1023) ntot = min(inc, ES_CAP);
    }
    __syncthreads();
    const int n = ntot;
    // cooperative run copy: 64 groups x 16 lanes
    {
        const int g = t >> 4, l = t & 15;
        for (int r = g; r < BP; r += 64) {
            const int len = rlen[r];
            const int base = r * CHUNK + rst[r];
            const int o = roff[r];
            for (int k = l; k < len; k += 16) {
                int p = o + k;
                if (p < ES_CAP) es[p] = col[base + k];
            }
        }
    }
    __syncthreads();
    if (t < BUCKN) cnt[t] = 0;
    __syncthreads();
    for (int i = t; i < n; i += 1024) atomicAdd(&cnt[(es[i] >> 17) & (BUCKN - 1)], 1);
    __syncthreads();
    {
        const int v = (t < BUCKN) ? cnt[t] : 0;
        const int inc = block_scan_incl(v, wtot, t);
        if (t < BUCKN) {
            int excl = inc - v;
            int node = buck * BUCKN + t;
            if (node < N) {
                deg[node] = v;
                row_start[node] = buck * STRIDE + excl;
            }
            cur[t] = excl;
        }
    }
    __syncthreads();
    for (int i = t; i < n; i += 1024) {
        int p = es[i];
        int pos = atomicAdd(&cur[(p >> 17) & (BUCKN - 1)], 1);
        pos = min(max(pos, 0), STRIDE - 1);
        col2[buck * STRIDE + pos] = p & 0x1FFFF;
    }
}

// ---------------- layer 1 transform: g1h = fp16( dis * (x @ W1^T) ) ----------------
__global__ __launch_bounds__(256) void k_xw1(
        const float* __restrict__ x, const float* __restrict__ W1,
        const int* __restrict__ deg, __half* __restrict__ g1h) {
    __shared__ float4 wtv[32 * 33];   // [kb][j] quad of W1[j][4kb..4kb+3], pad 33
    __shared__ float4 xsv[1024];      // 32 nodes x 32 k-quads
    const int t = threadIdx.x;
    const float4* W1v = (const float4*)W1;
    for (int idx = t; idx < 1024; idx += 256) {
        int j = idx >> 5, kb = idx & 31;
        wtv[kb * 33 + j] = W1v[idx];
    }
    const float4* x4 = (const float4*)x + (size_t)blockIdx.x * 1024;
    for (int idx = t; idx < 1024; idx += 256) xsv[idx] = x4[idx];
    __syncthreads();

    const int j = t & 31, ng = t >> 5;
    float a0 = 0.f, a1 = 0.f, a2 = 0.f, a3 = 0.f;
#pragma unroll 4
    for (int kb = 0; kb < 32; ++kb) {
        float4 w = wtv[kb * 33 + j];
        float4 x0 = xsv[(4 * ng + 0) * 32 + kb];
        float4 x1 = xsv[(4 * ng + 1) * 32 + kb];
        float4 x2 = xsv[(4 * ng + 2) * 32 + kb];
        float4 x3 = xsv[(4 * ng + 3) * 32 + kb];
        a0 = fmaf(w.x, x0.x, fmaf(w.y, x0.y, fmaf(w.z, x0.z, fmaf(w.w, x0.w, a0))));
        a1 = fmaf(w.x, x1.x, fmaf(w.y, x1.y, fmaf(w.z, x1.z, fmaf(w.w, x1.w, a1))));
        a2 = fmaf(w.x, x2.x, fmaf(w.y, x2.y, fmaf(w.z, x2.z, fmaf(w.w, x2.w, a2))));
        a3 = fmaf(w.x, x3.x, fmaf(w.y, x3.y, fmaf(w.z, x3.z, fmaf(w.w, x3.w, a3))));
    }
    const int nb = blockIdx.x * 32 + 4 * ng;
    g1h[(nb + 0) * 32 + j] = __float2half(a0 * rsqrtf((float)(deg[nb + 0] + 1)));
    g1h[(nb + 1) * 32 + j] = __float2half(a1 * rsqrtf((float)(deg[nb + 1] + 1)));
    g1h[(nb + 2) * 32 + j] = __float2half(a2 * rsqrtf((float)(deg[nb + 2] + 1)));
    g1h[(nb + 3) * 32 + j] = __float2half(a3 * rsqrtf((float)(deg[nb + 3] + 1)));
}

// ---------------- gather layer 1 + FUSED layer-2 transform (lean tail) ----------------
// Index prefetch: window n+1's col2 loads issue before window n's FMA tail.
__global__ __launch_bounds__(256) void k_gather1(
        const int* __restrict__ row_start, const int* __restrict__ deg,
        const int* __restrict__ col2, const __half* __restrict__ g1h,
        const float* __restrict__ b1, const float* __restrict__ W2,
        __half* __restrict__ g2h) {
    __shared__ float h1s[64 * 33];   // 8.4 KB, pad 33
    __shared__ float w2t[32 * 17];   // W2 transposed [k][j], pad 17
    const int t = threadIdx.x;
    for (int idx = t; idx < 512; idx += 256) {
        int j = idx >> 5, k = idx & 31;
        w2t[k * 17 + j] = W2[idx];
    }
    const int lane = t & 63, w = t >> 6;
    const int q = lane & 3;                      // feature octet
    const int nloc = w * 16 + (lane >> 2);
    const int node = blockIdx.x * 64 + nloc;
    const int nc = node < N ? node : N - 1;
    const int rs = row_start[nc];
    const int ne = (node < N) ? deg[nc] : 0;
    const uint4* g1v = (const uint4*)g1h;

    float acc[8];
    {
        uint4 rv = g1v[nc * 4 + q];
        const __half2* hp = (const __half2*)&rv;
#pragma unroll
        for (int m2 = 0; m2 < 4; ++m2) {
            float2 f = __half22float2(hp[m2]);
            acc[2 * m2] = f.x;
            acc[2 * m2 + 1] = f.y;
        }
    }
    int svN[4];
#pragma unroll
    for (int c = 0; c < 4; ++c)
        svN[c] = (4 * c + q < ne) ? col2[rs + 4 * c + q] : 0;
    for (int base = 0; base < ne; base += 16) {
        int sv[4];
#pragma unroll
        for (int c = 0; c < 4; ++c) sv[c] = svN[c];
        const int nb2 = base + 16;
        if (nb2 < ne) {
#pragma unroll
            for (int c = 0; c < 4; ++c)
                svN[c] = (nb2 + 4 * c + q < ne) ? col2[rs + nb2 + 4 * c + q] : 0;
        }
        int idx[16];
#pragma unroll
        for (int c = 0; c < 4; ++c)
#pragma unroll
            for (int u = 0; u < 4; ++u)
                idx[4 * c + u] = min(__shfl(sv[c], u, 4), N - 1);
        uint4 rv[16];
#pragma unroll
        for (int u = 0; u < 16; ++u) rv[u] = g1v[idx[u] * 4 + q];
#pragma unroll
        for (int u = 0; u < 16; ++u) {
            float wt = (base + u < ne) ? 1.f : 0.f;
            const __half2* hp = (const __half2*)&rv[u];
#pragma unroll
            for (int m2 = 0; m2 < 4; ++m2) {
                float2 f = __half22float2(hp[m2]);
                acc[2 * m2]     = fmaf(wt, f.x, acc[2 * m2]);
                acc[2 * m2 + 1] = fmaf(wt, f.y, acc[2 * m2 + 1]);
            }
        }
    }
    {
        const float dis = rsqrtf((float)(ne + 1));
#pragma unroll
        for (int u = 0; u < 8; ++u) {
            float v = (node < N) ? (acc[u] * dis + b1[q * 8 + u]) : 0.f;
            h1s[nloc * 33 + q * 8 + u] = v > 0.f ? v : 0.f;
        }
    }
    __syncthreads();
    const int n2 = t >> 2, jq = (t & 3) * 4;
    const int node2 = blockIdx.x * 64 + n2;
    if (node2 < N) {
        float a0 = 0.f, a1 = 0.f, a2 = 0.f, a3 = 0.f;
        const float* hr = h1s + n2 * 33;
#pragma unroll
        for (int k = 0; k < 32; ++k) {
            float h = hr[k];
            a0 = fmaf(h, w2t[k * 17 + jq + 0], a0);
            a1 = fmaf(h, w2t[k * 17 + jq + 1], a1);
            a2 = fmaf(h, w2t[k * 17 + jq + 2], a2);
            a3 = fmaf(h, w2t[k * 17 + jq + 3], a3);
        }
        const float dis2 = rsqrtf((float)(deg[node2] + 1));
        __half2* g2p = (__half2*)(g2h + node2 * 16 + jq);
        g2p[0] = __floats2half2_rn(a0 * dis2, a1 * dis2);
        g2p[1] = __floats2half2_rn(a2 * dis2, a3 * dis2);
    }
}

// ---------------- gather layer 2 (lean; LSTM separate for occupancy) ----------------
__global__ __launch_bounds__(256) void k_gather2(
        const int* __restrict__ row_start, const int* __restrict__ deg,
        const int* __restrict__ col2, const __half* __restrict__ g2h,
        const float* __restrict__ b2, float* __restrict__ h2) {
    const int t = threadIdx.x;
    const int lane = t & 63, w = t >> 6;
    const int q = lane & 1;
    const int node = blockIdx.x * 128 + w * 32 + (lane >> 1);
    const int nc = node < N ? node : N - 1;
    const int rs = row_start[nc];
    const int ne = (node < N) ? deg[nc] : 0;
    const uint4* g2v = (const uint4*)g2h;

    float acc[8];
    {
        uint4 rv = g2v[nc * 2 + q];
        const __half2* hp = (const __half2*)&rv;
#pragma unroll
        for (int m2 = 0; m2 < 4; ++m2) {
            float2 f = __half22float2(hp[m2]);
            acc[2 * m2] = f.x;
            acc[2 * m2 + 1] = f.y;
        }
    }
    int svN[8];
#pragma unroll
    for (int c = 0; c < 8; ++c)
        svN[c] = (2 * c + q < ne) ? col2[rs + 2 * c + q] : 0;
    for (int base = 0; base < ne; base += 16) {
        int sv[8];
#pragma unroll
        for (int c = 0; c < 8; ++c) sv[c] = svN[c];
        const int nb2 = base + 16;
        if (nb2 < ne) {
#pragma unroll
            for (int c = 0; c < 8; ++c)
                svN[c] = (nb2 + 2 * c + q < ne) ? col2[rs + nb2 + 2 * c + q] : 0;
        }
        int idx[16];
#pragma unroll
        for (int c = 0; c < 8; ++c) {
            idx[2 * c]     = min(__shfl(sv[c], 0, 2), N - 1);
            idx[2 * c + 1] = min(__shfl(sv[c], 1, 2), N - 1);
        }
        uint4 rv[16];
#pragma unroll
        for (int u = 0; u < 16; ++u) rv[u] = g2v[idx[u] * 2 + q];
#pragma unroll
        for (int u = 0; u < 16; ++u) {
            float wt = (base + u < ne) ? 1.f : 0.f;
            const __half2* hp = (const __half2*)&rv[u];
#pragma unroll
            for (int m2 = 0; m2 < 4; ++m2) {
                float2 f = __half22float2(hp[m2]);
                acc[2 * m2]     = fmaf(wt, f.x, acc[2 * m2]);
                acc[2 * m2 + 1] = fmaf(wt, f.y, acc[2 * m2 + 1]);
            }
        }
    }
    if (node < N) {
        const float dis = rsqrtf((float)(ne + 1));
        float4* h2v = (float4*)h2;
#pragma unroll
        for (int h = 0; h < 2; ++h) {
            float4 o;
            float v0 = acc[4 * h + 0] * dis + b2[q * 8 + 4 * h + 0];
            float v1 = acc[4 * h + 1] * dis + b2[q * 8 + 4 * h + 1];
            float v2 = acc[4 * h + 2] * dis + b2[q * 8 + 4 * h + 2];
            float v3 = acc[4 * h + 3] * dis + b2[q * 8 + 4 * h + 3];
            o.x = v0 > 0.f ? v0 : 0.f;
            o.y = v1 > 0.f ? v1 : 0.f;
            o.z = v2 > 0.f ? v2 : 0.f;
            o.w = v3 > 0.f ? v3 : 0.f;
            h2v[node * 4 + q * 2 + h] = o;
        }
    }
}

// ---------------- LSTM (h0=c0=0) + output head ----------------
__global__ __launch_bounds__(256) void k_final(
        const float* __restrict__ h2g,
        const float* __restrict__ w_ih, const float* __restrict__ b_ih,
        const float* __restrict__ b_hh, const float* __restrict__ W_out,
        const float* __restrict__ b_out, float* __restrict__ out) {
    __shared__ float wih[512];
    __shared__ float bias[32];
    __shared__ float wout[8];
    __shared__ float bo;
    const int t = threadIdx.x;
    for (int idx = t; idx < 512; idx += 256) wih[idx] = w_ih[idx];
    if (t < 32) bias[t] = b_ih[t] + b_hh[t];
    if (t < 8)  wout[t] = W_out[t];
    if (t == 0) bo = b_out[0];
    __syncthreads();

    const int i = blockIdx.x * 256 + t;
    if (i >= N) return;
    float h2[16];
    const float4* a4 = (const float4*)(h2g + (size_t)i * 16);
#pragma unroll
    for (int q = 0; q < 4; ++q) {
        float4 v = a4[q];
        h2[q * 4 + 0] = v.x; h2[q * 4 + 1] = v.y;
        h2[q * 4 + 2] = v.z; h2[q * 4 + 3] = v.w;
    }
    float oacc = 0.f;
#pragma unroll
    for (int q = 0; q < 8; ++q) {
        float gi = bias[q], gg = bias[16 + q], go = bias[24 + q];
#pragma unroll
        for (int k = 0; k < 16; ++k) {
            gi = fmaf(h2[k], wih[q * 16 + k], gi);
            gg = fmaf(h2[k], wih[(16 + q) * 16 + k], gg);
            go = fmaf(h2[k], wih[(24 + q) * 16 + k], go);
        }
        float c  = (1.f / (1.f + expf(-gi))) * tanhf(gg);
        float hh = (1.f / (1.f + expf(-go))) * tanhf(c);
        oacc = fmaf(hh, wout[q], oacc);
    }
    out[i] = oacc + bo;
}

extern "C" void kernel_launch(void* const* d_in, const int* in_sizes, int n_in,
                              void* d_out, int out_size, void* d_ws, size_t ws_size,
                              hipStream_t stream) {
    const float* x     = (const float*)d_in[0];
    const int*   ei    = (const int*)d_in[1];
    const float* W1    = (const float*)d_in[2];
    const float* b1    = (const float*)d_in[3];
    const float* W2    = (const float*)d_in[4];
    const float* b2    = (const float*)d_in[5];
    const float* w_ih  = (const float*)d_in[6];
    // d_in[7] = w_hh: unused (h0 = 0)
    const float* b_ih  = (const float*)d_in[8];
    const float* b_hh  = (const float*)d_in[9];
    const float* W_out = (const float*)d_in[10];
    const float* b_out = (const float*)d_in[11];
    float* out = (float*)d_out;

    const int E = in_sizes[1] / 2;
    const int* src = ei;
    const int* dst = ei + E;
    int BP = (E + CHUNK - 1) / CHUNK;   // 391
    if (BP > BPMAX) BP = BPMAX;

    // workspace (4 B units); disjoint regions; base offsets stay 16 B aligned
    int* col       = (int*)d_ws;                        // BPMAX*CHUNK
    int* hdr       = col + (size_t)BPMAX * CHUNK;       // BPMAX*HDRS
    int* col2      = hdr + (size_t)BPMAX * HDRS;        // COLCAP
    int* deg       = col2 + COLCAP;                     // N
    int* row_start = deg + N;                           // N
    int* base2     = row_start + N;
    __half* g1h    = (__half*)base2;                      // N*32 halves = N*16 ints
    __half* g2h    = (__half*)(base2 + (size_t)N * 16);   // N*16 halves = N*8 ints
    float* h2      = (float*)(base2 + (size_t)N * 24);    // N*16 floats

    k_part   <<<BP,              1024, 0, stream>>>(src, dst, col, hdr, E);
    k_sort   <<<NBUCK,           1024, 0, stream>>>(col, hdr, col2, deg, row_start, BP);
    k_xw1    <<<N / 32,          256,  0, stream>>>(x, W1, deg, g1h);
    k_gather1<<<(N + 63) / 64,   256,  0, stream>>>(row_start, deg, col2, g1h, b1, W2, g2h);
    k_gather2<<<(N + 127) / 128, 256,  0, stream>>>(row_start, deg, col2, g2h, b2, h2);
    k_final  <<<(N + 255) / 256, 256,  0, stream>>>(h2, w_ih, b_ih, b_hh, W_out, b_out, out);
}

// Round 17
// 239.364 us; speedup vs baseline: 1.0933x; 1.0280x over previous
//
#include <hip/hip_runtime.h>
#include <hip/hip_fp16.h>
#include <math.h>

static constexpr int N = 100000;
static constexpr int SHIFT = 7;                        // 128 nodes / bucket
static constexpr int BUCKN = 1 << SHIFT;               // 128
static constexpr int NBUCK = (N + BUCKN - 1) >> SHIFT; // 782
static constexpr int HDRS  = NBUCK + 1;                // 783 offsets per block
static constexpr int CHUNK = 8192;                     // edges per partition block
static constexpr int BPMAX = 512;                      // max partition blocks supported
static constexpr int STRIDE = 5120;                    // per-bucket CSR capacity (16 sigma)
static constexpr int COLCAP = NBUCK * STRIDE;
static constexpr int ES_CAP = STRIDE;

// inclusive block scan over 1024 threads via wave shuffles (2 barriers + 1 guard)
__device__ __forceinline__ int block_scan_incl(int v, int* wtot, int t) {
    const int lane = t & 63, wv = t >> 6;
    int x = v;
#pragma unroll
    for (int o = 1; o < 64; o <<= 1) {
        int y = __shfl_up(x, o, 64);
        if (lane >= o) x += y;
    }
    __syncthreads();                 // protect wtot reuse across calls
    if (lane == 63) wtot[wv] = x;
    __syncthreads();
    if (t < 16) {
        int y = wtot[t];
#pragma unroll
        for (int o = 1; o < 16; o <<= 1) {
            int z = __shfl_up(y, o, 16);
            if (t >= o) y += z;
        }
        wtot[t] = y;
    }
    __syncthreads();
    return x + (wv ? wtot[wv - 1] : 0);
}

// ---------------- partition: per-block LDS counting sort, COALESCED + int4 I/O ----------------
__global__ __launch_bounds__(1024) void k_part(const int* __restrict__ src,
                                               const int* __restrict__ dst,
                                               int* __restrict__ col,
                                               int* __restrict__ hdr, int E) {
    __shared__ __align__(16) int stage[CHUNK];     // 32 KB
    __shared__ int hl[NBUCK];
    __shared__ int cur[NBUCK];
    __shared__ int wtot[16];
    const int t = threadIdx.x, b = blockIdx.x;
    if (t < NBUCK) hl[t] = 0;        // 1024 >= NBUCK: single-shot OK
    __syncthreads();
    const int e0 = b * CHUNK;
    const int m = min(CHUNK, E - e0);
    const int m4 = m >> 2;
    const int4* d4 = (const int4*)(dst + e0);
    for (int i = t; i < m4; i += 1024) {
        int4 d = d4[i];
        atomicAdd(&hl[d.x >> SHIFT], 1);
        atomicAdd(&hl[d.y >> SHIFT], 1);
        atomicAdd(&hl[d.z >> SHIFT], 1);
        atomicAdd(&hl[d.w >> SHIFT], 1);
    }
    for (int i = (m4 << 2) + t; i < m; i += 1024) atomicAdd(&hl[dst[e0 + i] >> SHIFT], 1);
    __syncthreads();
    const int v = (t < NBUCK) ? hl[t] : 0;
    const int inc = block_scan_incl(v, wtot, t);
    if (t < NBUCK) {
        int excl = inc - v;
        cur[t] = excl;
        hdr[b * HDRS + t] = excl;
    }
    if (t == 0) hdr[b * HDRS + NBUCK] = m;
    __syncthreads();
    const int4* s4 = (const int4*)(src + e0);
    for (int i = t; i < m4; i += 1024) {
        int4 d = d4[i];
        int4 s = s4[i];
        int p;
        p = atomicAdd(&cur[d.x >> SHIFT], 1); p = min(max(p, 0), CHUNK - 1);
        stage[p] = (s.x & 0x1FFFF) | ((d.x & (BUCKN - 1)) << 17);
        p = atomicAdd(&cur[d.y >> SHIFT], 1); p = min(max(p, 0), CHUNK - 1);
        stage[p] = (s.y & 0x1FFFF) | ((d.y & (BUCKN - 1)) << 17);
        p = atomicAdd(&cur[d.z >> SHIFT], 1); p = min(max(p, 0), CHUNK - 1);
        stage[p] = (s.z & 0x1FFFF) | ((d.z & (BUCKN - 1)) << 17);
        p = atomicAdd(&cur[d.w >> SHIFT], 1); p = min(max(p, 0), CHUNK - 1);
        stage[p] = (s.w & 0x1FFFF) | ((d.w & (BUCKN - 1)) << 17);
    }
    for (int i = (m4 << 2) + t; i < m; i += 1024) {
        int d = dst[e0 + i];
        int p = atomicAdd(&cur[d >> SHIFT], 1);
        p = min(max(p, 0), CHUNK - 1);
        stage[p] = (src[e0 + i] & 0x1FFFF) | ((d & (BUCKN - 1)) << 17);
    }
    __syncthreads();
    int4* c4 = (int4*)(col + e0);
    const int4* st4 = (const int4*)stage;
    for (int i = t; i < m4; i += 1024) c4[i] = st4[i];              // sequential 16 B
    for (int i = (m4 << 2) + t; i < m; i += 1024) col[e0 + i] = stage[i];
}

// ---------------- per-bucket: gather runs (16-lane groups), sort -> CSR in col2 ----------------
__global__ __launch_bounds__(1024) void k_sort(const int* __restrict__ col,
                                               const int* __restrict__ hdr,
                                               int* __restrict__ col2,
                                               int* __restrict__ deg,
                                               int* __restrict__ row_start, int BP) {
    __shared__ int es[ES_CAP];       // 20 KB
    __shared__ int rlen[BPMAX];
    __shared__ int rst[BPMAX];
    __shared__ int roff[BPMAX];
    __shared__ int cnt[BUCKN];
    __shared__ int cur[BUCKN];
    __shared__ int wtot[16];
    __shared__ int ntot;
    const int t = threadIdx.x, buck = blockIdx.x;
    if (t < BPMAX) { rlen[t] = 0; rst[t] = 0; }
    __syncthreads();
    if (t < BP) {
        int a = hdr[t * HDRS + buck];
        int e = hdr[t * HDRS + buck + 1];
        rst[t] = min(max(a, 0), CHUNK);
        rlen[t] = min(max(e - a, 0), CHUNK);
    }
    __syncthreads();
    {
        const int v = (t < BPMAX) ? rlen[t] : 0;
        const int inc = block_scan_incl(v, wtot, t);
        if (t < BPMAX) roff[t] = inc - v;
        if (t == 1023) ntot = min(inc, ES_CAP);
    }
    __syncthreads();
    const int n = ntot;
    {
        const int g = t >> 4, l = t & 15;
        for (int r = g; r < BP; r += 64) {
            const int len = rlen[r];
            const int base = r * CHUNK + rst[r];
            const int o = roff[r];
            for (int k = l; k < len; k += 16) {
                int p = o + k;
                if (p < ES_CAP) es[p] = col[base + k];
            }
        }
    }
    __syncthreads();
    if (t < BUCKN) cnt[t] = 0;
    __syncthreads();
    for (int i = t; i < n; i += 1024) atomicAdd(&cnt[(es[i] >> 17) & (BUCKN - 1)], 1);
    __syncthreads();
    {
        const int v = (t < BUCKN) ? cnt[t] : 0;
        const int inc = block_scan_incl(v, wtot, t);
        if (t < BUCKN) {
            int excl = inc - v;
            int node = buck * BUCKN + t;
            if (node < N) {
                deg[node] = v;
                row_start[node] = buck * STRIDE + excl;
            }
            cur[t] = excl;
        }
    }
    __syncthreads();
    for (int i = t; i < n; i += 1024) {
        int p = es[i];
        int pos = atomicAdd(&cur[(p >> 17) & (BUCKN - 1)], 1);
        pos = min(max(pos, 0), STRIDE - 1);
        col2[buck * STRIDE + pos] = p & 0x1FFFF;
    }
}

// ---------------- layer 1 transform: g1h = fp16( dis * (x @ W1^T) ) ----------------
__global__ __launch_bounds__(256) void k_xw1(
        const float* __restrict__ x, const float* __restrict__ W1,
        const int* __restrict__ deg, __half* __restrict__ g1h) {
    __shared__ float4 wtv[32 * 33];   // [kb][j] quad of W1[j][4kb..4kb+3], pad 33
    __shared__ float4 xsv[1024];      // 32 nodes x 32 k-quads
    const int t = threadIdx.x;
    const float4* W1v = (const float4*)W1;
    for (int idx = t; idx < 1024; idx += 256) {
        int j = idx >> 5, kb = idx & 31;
        wtv[kb * 33 + j] = W1v[idx];
    }
    const float4* x4 = (const float4*)x + (size_t)blockIdx.x * 1024;
    for (int idx = t; idx < 1024; idx += 256) xsv[idx] = x4[idx];
    __syncthreads();

    const int j = t & 31, ng = t >> 5;
    float a0 = 0.f, a1 = 0.f, a2 = 0.f, a3 = 0.f;
#pragma unroll 4
    for (int kb = 0; kb < 32; ++kb) {
        float4 w = wtv[kb * 33 + j];
        float4 x0 = xsv[(4 * ng + 0) * 32 + kb];
        float4 x1 = xsv[(4 * ng + 1) * 32 + kb];
        float4 x2 = xsv[(4 * ng + 2) * 32 + kb];
        float4 x3 = xsv[(4 * ng + 3) * 32 + kb];
        a0 = fmaf(w.x, x0.x, fmaf(w.y, x0.y, fmaf(w.z, x0.z, fmaf(w.w, x0.w, a0))));
        a1 = fmaf(w.x, x1.x, fmaf(w.y, x1.y, fmaf(w.z, x1.z, fmaf(w.w, x1.w, a1))));
        a2 = fmaf(w.x, x2.x, fmaf(w.y, x2.y, fmaf(w.z, x2.z, fmaf(w.w, x2.w, a2))));
        a3 = fmaf(w.x, x3.x, fmaf(w.y, x3.y, fmaf(w.z, x3.z, fmaf(w.w, x3.w, a3))));
    }
    const int nb = blockIdx.x * 32 + 4 * ng;
    g1h[(nb + 0) * 32 + j] = __float2half(a0 * rsqrtf((float)(deg[nb + 0] + 1)));
    g1h[(nb + 1) * 32 + j] = __float2half(a1 * rsqrtf((float)(deg[nb + 1] + 1)));
    g1h[(nb + 2) * 32 + j] = __float2half(a2 * rsqrtf((float)(deg[nb + 2] + 1)));
    g1h[(nb + 3) * 32 + j] = __float2half(a3 * rsqrtf((float)(deg[nb + 3] + 1)));
}

// ---------------- gather layer 1 + FUSED layer-2 transform (lean tail) ----------------
__global__ __launch_bounds__(256) void k_gather1(
        const int* __restrict__ row_start, const int* __restrict__ deg,
        const int* __restrict__ col2, const __half* __restrict__ g1h,
        const float* __restrict__ b1, const float* __restrict__ W2,
        __half* __restrict__ g2h) {
    __shared__ float h1s[64 * 33];   // 8.4 KB, pad 33
    __shared__ float w2t[32 * 17];   // W2 transposed [k][j], pad 17
    const int t = threadIdx.x;
    for (int idx = t; idx < 512; idx += 256) {
        int j = idx >> 5, k = idx & 31;
        w2t[k * 17 + j] = W2[idx];
    }
    const int lane = t & 63, w = t >> 6;
    const int q = lane & 3;                      // feature octet
    const int nloc = w * 16 + (lane >> 2);
    const int node = blockIdx.x * 64 + nloc;
    const int nc = node < N ? node : N - 1;
    const int rs = row_start[nc];
    const int ne = (node < N) ? deg[nc] : 0;
    const uint4* g1v = (const uint4*)g1h;

    float acc[8];
    {
        uint4 rv = g1v[nc * 4 + q];
        const __half2* hp = (const __half2*)&rv;
#pragma unroll
        for (int m2 = 0; m2 < 4; ++m2) {
            float2 f = __half22float2(hp[m2]);
            acc[2 * m2] = f.x;
            acc[2 * m2 + 1] = f.y;
        }
    }
    int svN[4];
#pragma unroll
    for (int c = 0; c < 4; ++c)
        svN[c] = (4 * c + q < ne) ? col2[rs + 4 * c + q] : 0;
    for (int base = 0; base < ne; base += 16) {
        int sv[4];
#pragma unroll
        for (int c = 0; c < 4; ++c) sv[c] = svN[c];
        const int nb2 = base + 16;
        if (nb2 < ne) {
#pragma unroll
            for (int c = 0; c < 4; ++c)
                svN[c] = (nb2 + 4 * c + q < ne) ? col2[rs + nb2 + 4 * c + q] : 0;
        }
        int idx[16];
#pragma unroll
        for (int c = 0; c < 4; ++c)
#pragma unroll
            for (int u = 0; u < 4; ++u)
                idx[4 * c + u] = min(__shfl(sv[c], u, 4), N - 1);
        uint4 rv[16];
#pragma unroll
        for (int u = 0; u < 16; ++u) rv[u] = g1v[idx[u] * 4 + q];
#pragma unroll
        for (int u = 0; u < 16; ++u) {
            float wt = (base + u < ne) ? 1.f : 0.f;
            const __half2* hp = (const __half2*)&rv[u];
#pragma unroll
            for (int m2 = 0; m2 < 4; ++m2) {
                float2 f = __half22float2(hp[m2]);
                acc[2 * m2]     = fmaf(wt, f.x, acc[2 * m2]);
                acc[2 * m2 + 1] = fmaf(wt, f.y, acc[2 * m2 + 1]);
            }
        }
    }
    {
        const float dis = rsqrtf((float)(ne + 1));
#pragma unroll
        for (int u = 0; u < 8; ++u) {
            float v = (node < N) ? (acc[u] * dis + b1[q * 8 + u]) : 0.f;
            h1s[nloc * 33 + q * 8 + u] = v > 0.f ? v : 0.f;
        }
    }
    __syncthreads();
    const int n2 = t >> 2, jq = (t & 3) * 4;
    const int node2 = blockIdx.x * 64 + n2;
    if (node2 < N) {
        float a0 = 0.f, a1 = 0.f, a2 = 0.f, a3 = 0.f;
        const float* hr = h1s + n2 * 33;
#pragma unroll
        for (int k = 0; k < 32; ++k) {
            float h = hr[k];
            a0 = fmaf(h, w2t[k * 17 + jq + 0], a0);
            a1 = fmaf(h, w2t[k * 17 + jq + 1], a1);
            a2 = fmaf(h, w2t[k * 17 + jq + 2], a2);
            a3 = fmaf(h, w2t[k * 17 + jq + 3], a3);
        }
        const float dis2 = rsqrtf((float)(deg[node2] + 1));
        __half2* g2p = (__half2*)(g2h + node2 * 16 + jq);
        g2p[0] = __floats2half2_rn(a0 * dis2, a1 * dis2);
        g2p[1] = __floats2half2_rn(a2 * dis2, a3 * dis2);
    }
}

// ---------------- gather layer 2 + register-lean fused LSTM + head ----------------
// Node's 16 h2 feats stay split across its 2 lanes (8 each). Gates computed
// sequentially: lane-partial dots (float4 LDS reads of wih) + __shfl_xor
// combine -> ~6 extra live VGPRs (round-12's LDS-tile design hit 132 VGPR).
// h2 never touches global; k_final eliminated.
__global__ __launch_bounds__(256) void k_gather2(
        const int* __restrict__ row_start, const int* __restrict__ deg,
        const int* __restrict__ col2, const __half* __restrict__ g2h,
        const float* __restrict__ b2,
        const float* __restrict__ w_ih, const float* __restrict__ b_ih,
        const float* __restrict__ b_hh, const float* __restrict__ W_out,
        const float* __restrict__ b_out, float* __restrict__ out) {
    __shared__ __align__(16) float wihs[512];
    __shared__ float bias[32];
    __shared__ float wout[8];
    __shared__ float bo;
    const int t = threadIdx.x;
    for (int idx = t; idx < 512; idx += 256) wihs[idx] = w_ih[idx];
    if (t < 32) bias[t] = b_ih[t] + b_hh[t];
    if (t < 8)  wout[t] = W_out[t];
    if (t == 0) bo = b_out[0];
    __syncthreads();

    const int lane = t & 63, w = t >> 6;
    const int q = lane & 1;
    const int node = blockIdx.x * 128 + w * 32 + (lane >> 1);
    const int nc = node < N ? node : N - 1;
    const int rs = row_start[nc];
    const int ne = (node < N) ? deg[nc] : 0;
    const uint4* g2v = (const uint4*)g2h;

    float acc[8];
    {
        uint4 rv = g2v[nc * 2 + q];
        const __half2* hp = (const __half2*)&rv;
#pragma unroll
        for (int m2 = 0; m2 < 4; ++m2) {
            float2 f = __half22float2(hp[m2]);
            acc[2 * m2] = f.x;
            acc[2 * m2 + 1] = f.y;
        }
    }
    int svN[8];
#pragma unroll
    for (int c = 0; c < 8; ++c)
        svN[c] = (2 * c + q < ne) ? col2[rs + 2 * c + q] : 0;
    for (int base = 0; base < ne; base += 16) {
        int sv[8];
#pragma unroll
        for (int c = 0; c < 8; ++c) sv[c] = svN[c];
        const int nb2 = base + 16;
        if (nb2 < ne) {
#pragma unroll
            for (int c = 0; c < 8; ++c)
                svN[c] = (nb2 + 2 * c + q < ne) ? col2[rs + nb2 + 2 * c + q] : 0;
        }
        int idx[16];
#pragma unroll
        for (int c = 0; c < 8; ++c) {
            idx[2 * c]     = min(__shfl(sv[c], 0, 2), N - 1);
            idx[2 * c + 1] = min(__shfl(sv[c], 1, 2), N - 1);
        }
        uint4 rv[16];
#pragma unroll
        for (int u = 0; u < 16; ++u) rv[u] = g2v[idx[u] * 2 + q];
#pragma unroll
        for (int u = 0; u < 16; ++u) {
            float wt = (base + u < ne) ? 1.f : 0.f;
            const __half2* hp = (const __half2*)&rv[u];
#pragma unroll
            for (int m2 = 0; m2 < 4; ++m2) {
                float2 f = __half22float2(hp[m2]);
                acc[2 * m2]     = fmaf(wt, f.x, acc[2 * m2]);
                acc[2 * m2 + 1] = fmaf(wt, f.y, acc[2 * m2 + 1]);
            }
        }
    }
    // finalize h2 feats (lane q holds feats q*8..q*8+7) -> in-register relu
    {
        const float dis = rsqrtf((float)(ne + 1));
#pragma unroll
        for (int u = 0; u < 8; ++u) {
            float v = acc[u] * dis + b2[q * 8 + u];
            acc[u] = v > 0.f ? v : 0.f;
        }
    }
    // LSTM (h0=c0=0) + head, pair-cooperative; all lanes execute (shfl needs both)
    const float4* w4 = (const float4*)wihs;      // row g is w4[g*4 .. g*4+3]
    float oacc = 0.f;
#pragma unroll
    for (int g = 0; g < 8; ++g) {
        float4 wi0 = w4[g * 4 + q * 2],        wi1 = w4[g * 4 + q * 2 + 1];
        float4 wg0 = w4[(16 + g) * 4 + q * 2], wg1 = w4[(16 + g) * 4 + q * 2 + 1];
        float4 wo0 = w4[(24 + g) * 4 + q * 2], wo1 = w4[(24 + g) * 4 + q * 2 + 1];
        float gi = acc[0] * wi0.x + acc[1] * wi0.y + acc[2] * wi0.z + acc[3] * wi0.w
                 + acc[4] * wi1.x + acc[5] * wi1.y + acc[6] * wi1.z + acc[7] * wi1.w;
        float gg = acc[0] * wg0.x + acc[1] * wg0.y + acc[2] * wg0.z + acc[3] * wg0.w
                 + acc[4] * wg1.x + acc[5] * wg1.y + acc[6] * wg1.z + acc[7] * wg1.w;
        float go = acc[0] * wo0.x + acc[1] * wo0.y + acc[2] * wo0.z + acc[3] * wo0.w
                 + acc[4] * wo1.x + acc[5] * wo1.y + acc[6] * wo1.z + acc[7] * wo1.w;
        gi = gi + __shfl_xor(gi, 1, 2) + bias[g];
        gg = gg + __shfl_xor(gg, 1, 2) + bias[16 + g];
        go = go + __shfl_xor(go, 1, 2) + bias[24 + g];
        float c  = (1.f / (1.f + expf(-gi))) * tanhf(gg);
        float hh = (1.f / (1.f + expf(-go))) * tanhf(c);
        oacc = fmaf(hh, wout[g], oacc);
    }
    if (node < N && q == 0) out[node] = oacc + bo;
}

extern "C" void kernel_launch(void* const* d_in, const int* in_sizes, int n_in,
                              void* d_out, int out_size, void* d_ws, size_t ws_size,
                              hipStream_t stream) {
    const float* x     = (const float*)d_in[0];
    const int*   ei    = (const int*)d_in[1];
    const float* W1    = (const float*)d_in[2];
    const float* b1    = (const float*)d_in[3];
    const float* W2    = (const float*)d_in[4];
    const float* b2    = (const float*)d_in[5];
    const float* w_ih  = (const float*)d_in[6];
    // d_in[7] = w_hh: unused (h0 = 0)
    const float* b_ih  = (const float*)d_in[8];
    const float* b_hh  = (const float*)d_in[9];
    const float* W_out = (const float*)d_in[10];
    const float* b_out = (const float*)d_in[11];
    float* out = (float*)d_out;

    const int E = in_sizes[1] / 2;
    const int* src = ei;
    const int* dst = ei + E;
    int BP = (E + CHUNK - 1) / CHUNK;   // 391
    if (BP > BPMAX) BP = BPMAX;

    // workspace (4 B units); disjoint regions; base offsets stay 16 B aligned
    int* col       = (int*)d_ws;                        // BPMAX*CHUNK
    int* hdr       = col + (size_t)BPMAX * CHUNK;       // BPMAX*HDRS
    int* col2      = hdr + (size_t)BPMAX * HDRS;        // COLCAP
    int* deg       = col2 + COLCAP;                     // N
    int* row_start = deg + N;                           // N
    int* base2     = row_start + N;
    __half* g1h    = (__half*)base2;                      // N*32 halves = N*16 ints
    __half* g2h    = (__half*)(base2 + (size_t)N * 16);   // N*16 halves = N*8 ints

    k_part   <<<BP,              1024, 0, stream>>>(src, dst, col, hdr, E);
    k_sort   <<<NBUCK,           1024, 0, stream>>>(col, hdr, col2, deg, row_start, BP);
    k_xw1    <<<N / 32,          256,  0, stream>>>(x, W1, deg, g1h);
    k_gather1<<<(N + 63) / 64,   256,  0, stream>>>(row_start, deg, col2, g1h, b1, W2, g2h);
    k_gather2<<<(N + 127) / 128, 256,  0, stream>>>(row_start, deg, col2, g2h, b2,
                                                    w_ih, b_ih, b_hh, W_out, b_out, out);
}

// Round 18
// 230.702 us; speedup vs baseline: 1.1343x; 1.0375x over previous
//
#include <hip/hip_runtime.h>
#include <hip/hip_fp16.h>
#include <math.h>

static constexpr int N = 100000;
static constexpr int SHIFT = 7;                        // 128 nodes / bucket
static constexpr int BUCKN = 1 << SHIFT;               // 128
static constexpr int NBUCK = (N + BUCKN - 1) >> SHIFT; // 782
static constexpr int HDRS  = NBUCK + 1;                // 783 offsets per block
static constexpr int CHUNK = 8192;                     // edges per partition block
static constexpr int BPMAX = 512;                      // max partition blocks supported
static constexpr int STRIDE = 5120;                    // per-bucket CSR capacity (16 sigma)
static constexpr int COLCAP = NBUCK * STRIDE;
static constexpr int ES_CAP = STRIDE;

// inclusive block scan over 1024 threads via wave shuffles
__device__ __forceinline__ int block_scan_incl(int v, int* wtot, int t) {
    const int lane = t & 63, wv = t >> 6;
    int x = v;
#pragma unroll
    for (int o = 1; o < 64; o <<= 1) {
        int y = __shfl_up(x, o, 64);
        if (lane >= o) x += y;
    }
    __syncthreads();                 // protect wtot reuse across calls
    if (lane == 63) wtot[wv] = x;
    __syncthreads();
    if (t < 16) {
        int y = wtot[t];
#pragma unroll
        for (int o = 1; o < 16; o <<= 1) {
            int z = __shfl_up(y, o, 16);
            if (t >= o) y += z;
        }
        wtot[t] = y;
    }
    __syncthreads();
    return x + (wv ? wtot[wv - 1] : 0);
}

// ---------------- partition: per-block LDS counting sort, COALESCED + int4 I/O ----------------
__global__ __launch_bounds__(1024) void k_part(const int* __restrict__ src,
                                               const int* __restrict__ dst,
                                               int* __restrict__ col,
                                               int* __restrict__ hdr, int E) {
    __shared__ __align__(16) int stage[CHUNK];     // 32 KB
    __shared__ int hl[NBUCK];
    __shared__ int cur[NBUCK];
    __shared__ int wtot[16];
    const int t = threadIdx.x, b = blockIdx.x;
    if (t < NBUCK) hl[t] = 0;        // 1024 >= NBUCK: single-shot OK
    __syncthreads();
    const int e0 = b * CHUNK;
    const int m = min(CHUNK, E - e0);
    const int m4 = m >> 2;
    const int4* d4 = (const int4*)(dst + e0);
    for (int i = t; i < m4; i += 1024) {
        int4 d = d4[i];
        atomicAdd(&hl[d.x >> SHIFT], 1);
        atomicAdd(&hl[d.y >> SHIFT], 1);
        atomicAdd(&hl[d.z >> SHIFT], 1);
        atomicAdd(&hl[d.w >> SHIFT], 1);
    }
    for (int i = (m4 << 2) + t; i < m; i += 1024) atomicAdd(&hl[dst[e0 + i] >> SHIFT], 1);
    __syncthreads();
    const int v = (t < NBUCK) ? hl[t] : 0;
    const int inc = block_scan_incl(v, wtot, t);
    if (t < NBUCK) {
        int excl = inc - v;
        cur[t] = excl;
        hdr[b * HDRS + t] = excl;
    }
    if (t == 0) hdr[b * HDRS + NBUCK] = m;
    __syncthreads();
    const int4* s4 = (const int4*)(src + e0);
    for (int i = t; i < m4; i += 1024) {
        int4 d = d4[i];
        int4 s = s4[i];
        int p;
        p = atomicAdd(&cur[d.x >> SHIFT], 1); p = min(max(p, 0), CHUNK - 1);
        stage[p] = (s.x & 0x1FFFF) | ((d.x & (BUCKN - 1)) << 17);
        p = atomicAdd(&cur[d.y >> SHIFT], 1); p = min(max(p, 0), CHUNK - 1);
        stage[p] = (s.y & 0x1FFFF) | ((d.y & (BUCKN - 1)) << 17);
        p = atomicAdd(&cur[d.z >> SHIFT], 1); p = min(max(p, 0), CHUNK - 1);
        stage[p] = (s.z & 0x1FFFF) | ((d.z & (BUCKN - 1)) << 17);
        p = atomicAdd(&cur[d.w >> SHIFT], 1); p = min(max(p, 0), CHUNK - 1);
        stage[p] = (s.w & 0x1FFFF) | ((d.w & (BUCKN - 1)) << 17);
    }
    for (int i = (m4 << 2) + t; i < m; i += 1024) {
        int d = dst[e0 + i];
        int p = atomicAdd(&cur[d >> SHIFT], 1);
        p = min(max(p, 0), CHUNK - 1);
        stage[p] = (src[e0 + i] & 0x1FFFF) | ((d & (BUCKN - 1)) << 17);
    }
    __syncthreads();
    int4* c4 = (int4*)(col + e0);
    const int4* st4 = (const int4*)stage;
    for (int i = t; i < m4; i += 1024) c4[i] = st4[i];              // sequential 16 B
    for (int i = (m4 << 2) + t; i < m; i += 1024) col[e0 + i] = stage[i];
}

// ---------------- per-bucket: gather runs, sort in LDS, SEQUENTIAL col2 writeback ----------------
__global__ __launch_bounds__(1024) void k_sort(const int* __restrict__ col,
                                               const int* __restrict__ hdr,
                                               int* __restrict__ col2,
                                               int* __restrict__ deg,
                                               int2* __restrict__ rsdeg, int BP) {
    __shared__ int es[ES_CAP];                 // 20 KB
    __shared__ __align__(16) int es2[ES_CAP];  // 20 KB (sorted output staging)
    __shared__ int rlen[BPMAX];
    __shared__ int rst[BPMAX];
    __shared__ int roff[BPMAX];
    __shared__ int cnt[BUCKN];
    __shared__ int cur[BUCKN];
    __shared__ int wtot[16];
    __shared__ int ntot;
    const int t = threadIdx.x, buck = blockIdx.x;
    if (t < BPMAX) { rlen[t] = 0; rst[t] = 0; }
    __syncthreads();
    if (t < BP) {
        int a = hdr[t * HDRS + buck];
        int e = hdr[t * HDRS + buck + 1];
        rst[t] = min(max(a, 0), CHUNK);
        rlen[t] = min(max(e - a, 0), CHUNK);
    }
    __syncthreads();
    {
        const int v = (t < BPMAX) ? rlen[t] : 0;
        const int inc = block_scan_incl(v, wtot, t);
        if (t < BPMAX) roff[t] = inc - v;
        if (t == 1023) ntot = min(inc, ES_CAP);
    }
    __syncthreads();
    const int n = ntot;
    {   // cooperative run copy: 64 groups x 16 lanes
        const int g = t >> 4, l = t & 15;
        for (int r = g; r < BP; r += 64) {
            const int len = rlen[r];
            const int base = r * CHUNK + rst[r];
            const int o = roff[r];
            for (int k = l; k < len; k += 16) {
                int p = o + k;
                if (p < ES_CAP) es[p] = col[base + k];
            }
        }
    }
    __syncthreads();
    if (t < BUCKN) cnt[t] = 0;
    __syncthreads();
    for (int i = t; i < n; i += 1024) atomicAdd(&cnt[(es[i] >> 17) & (BUCKN - 1)], 1);
    __syncthreads();
    {
        const int v = (t < BUCKN) ? cnt[t] : 0;
        const int inc = block_scan_incl(v, wtot, t);
        if (t < BUCKN) {
            int excl = inc - v;
            int node = buck * BUCKN + t;
            if (node < N) {
                deg[node] = v;
                rsdeg[node] = make_int2(buck * STRIDE + excl, v);
            }
            cur[t] = excl;
        }
    }
    __syncthreads();
    for (int i = t; i < n; i += 1024) {          // scatter within LDS (cheap)
        int p = es[i];
        int pos = atomicAdd(&cur[(p >> 17) & (BUCKN - 1)], 1);
        pos = min(max(pos, 0), ES_CAP - 1);
        es2[pos] = p & 0x1FFFF;
    }
    __syncthreads();
    {   // sequential int4 writeback (round-17 did 3.2M random 4-B global stores)
        const int n4 = n >> 2;
        int4* o4 = (int4*)(col2 + buck * STRIDE);
        const int4* e4 = (const int4*)es2;
        for (int i = t; i < n4; i += 1024) o4[i] = e4[i];
        for (int i = (n4 << 2) + t; i < n; i += 1024) col2[buck * STRIDE + i] = es2[i];
    }
}

// ---------------- layer 1 transform: g1h = fp16( dis * (x @ W1^T) ) ----------------
__global__ __launch_bounds__(256) void k_xw1(
        const float* __restrict__ x, const float* __restrict__ W1,
        const int* __restrict__ deg, __half* __restrict__ g1h) {
    __shared__ float4 wtv[32 * 33];   // [kb][j] quad of W1[j][4kb..4kb+3], pad 33
    __shared__ float4 xsv[1024];      // 32 nodes x 32 k-quads
    const int t = threadIdx.x;
    const float4* W1v = (const float4*)W1;
    for (int idx = t; idx < 1024; idx += 256) {
        int j = idx >> 5, kb = idx & 31;
        wtv[kb * 33 + j] = W1v[idx];
    }
    const float4* x4 = (const float4*)x + (size_t)blockIdx.x * 1024;
    for (int idx = t; idx < 1024; idx += 256) xsv[idx] = x4[idx];
    __syncthreads();

    const int j = t & 31, ng = t >> 5;
    float a0 = 0.f, a1 = 0.f, a2 = 0.f, a3 = 0.f;
#pragma unroll 4
    for (int kb = 0; kb < 32; ++kb) {
        float4 w = wtv[kb * 33 + j];
        float4 x0 = xsv[(4 * ng + 0) * 32 + kb];
        float4 x1 = xsv[(4 * ng + 1) * 32 + kb];
        float4 x2 = xsv[(4 * ng + 2) * 32 + kb];
        float4 x3 = xsv[(4 * ng + 3) * 32 + kb];
        a0 = fmaf(w.x, x0.x, fmaf(w.y, x0.y, fmaf(w.z, x0.z, fmaf(w.w, x0.w, a0))));
        a1 = fmaf(w.x, x1.x, fmaf(w.y, x1.y, fmaf(w.z, x1.z, fmaf(w.w, x1.w, a1))));
        a2 = fmaf(w.x, x2.x, fmaf(w.y, x2.y, fmaf(w.z, x2.z, fmaf(w.w, x2.w, a2))));
        a3 = fmaf(w.x, x3.x, fmaf(w.y, x3.y, fmaf(w.z, x3.z, fmaf(w.w, x3.w, a3))));
    }
    const int nb = blockIdx.x * 32 + 4 * ng;
    g1h[(nb + 0) * 32 + j] = __float2half(a0 * rsqrtf((float)(deg[nb + 0] + 1)));
    g1h[(nb + 1) * 32 + j] = __float2half(a1 * rsqrtf((float)(deg[nb + 1] + 1)));
    g1h[(nb + 2) * 32 + j] = __float2half(a2 * rsqrtf((float)(deg[nb + 2] + 1)));
    g1h[(nb + 3) * 32 + j] = __float2half(a3 * rsqrtf((float)(deg[nb + 3] + 1)));
}

// ---------------- gather layer 1 + FUSED layer-2 transform (lean tail) ----------------
__global__ __launch_bounds__(256) void k_gather1(
        const int2* __restrict__ rsdeg,
        const int* __restrict__ col2, const __half* __restrict__ g1h,
        const float* __restrict__ b1, const float* __restrict__ W2,
        __half* __restrict__ g2h) {
    __shared__ float h1s[64 * 33];   // 8.4 KB, pad 33
    __shared__ float w2t[32 * 17];   // W2 transposed [k][j], pad 17
    const int t = threadIdx.x;
    for (int idx = t; idx < 512; idx += 256) {
        int j = idx >> 5, k = idx & 31;
        w2t[k * 17 + j] = W2[idx];
    }
    const int lane = t & 63, w = t >> 6;
    const int q = lane & 3;                      // feature octet
    const int nloc = w * 16 + (lane >> 2);
    const int node = blockIdx.x * 64 + nloc;
    const int nc = node < N ? node : N - 1;
    const int2 rd = rsdeg[nc];
    const int rs = rd.x;
    const int ne = (node < N) ? rd.y : 0;
    const uint4* g1v = (const uint4*)g1h;

    float acc[8];
    {
        uint4 rv = g1v[nc * 4 + q];
        const __half2* hp = (const __half2*)&rv;
#pragma unroll
        for (int m2 = 0; m2 < 4; ++m2) {
            float2 f = __half22float2(hp[m2]);
            acc[2 * m2] = f.x;
            acc[2 * m2 + 1] = f.y;
        }
    }
    int svN[4];
#pragma unroll
    for (int c = 0; c < 4; ++c)
        svN[c] = (4 * c + q < ne) ? col2[rs + 4 * c + q] : 0;
    for (int base = 0; base < ne; base += 16) {
        int sv[4];
#pragma unroll
        for (int c = 0; c < 4; ++c) sv[c] = svN[c];
        const int nb2 = base + 16;
        if (nb2 < ne) {
#pragma unroll
            for (int c = 0; c < 4; ++c)
                svN[c] = (nb2 + 4 * c + q < ne) ? col2[rs + nb2 + 4 * c + q] : 0;
        }
        int idx[16];
#pragma unroll
        for (int c = 0; c < 4; ++c)
#pragma unroll
            for (int u = 0; u < 4; ++u)
                idx[4 * c + u] = min(__shfl(sv[c], u, 4), N - 1);
        uint4 rv[16];
#pragma unroll
        for (int u = 0; u < 16; ++u) rv[u] = g1v[idx[u] * 4 + q];
#pragma unroll
        for (int u = 0; u < 16; ++u) {
            float wt = (base + u < ne) ? 1.f : 0.f;
            const __half2* hp = (const __half2*)&rv[u];
#pragma unroll
            for (int m2 = 0; m2 < 4; ++m2) {
                float2 f = __half22float2(hp[m2]);
                acc[2 * m2]     = fmaf(wt, f.x, acc[2 * m2]);
                acc[2 * m2 + 1] = fmaf(wt, f.y, acc[2 * m2 + 1]);
            }
        }
    }
    {
        const float dis = rsqrtf((float)(ne + 1));
#pragma unroll
        for (int u = 0; u < 8; ++u) {
            float v = (node < N) ? (acc[u] * dis + b1[q * 8 + u]) : 0.f;
            h1s[nloc * 33 + q * 8 + u] = v > 0.f ? v : 0.f;
        }
    }
    __syncthreads();
    const int n2 = t >> 2, jq = (t & 3) * 4;
    const int node2 = blockIdx.x * 64 + n2;
    if (node2 < N) {
        float a0 = 0.f, a1 = 0.f, a2 = 0.f, a3 = 0.f;
        const float* hr = h1s + n2 * 33;
#pragma unroll
        for (int k = 0; k < 32; ++k) {
            float h = hr[k];
            a0 = fmaf(h, w2t[k * 17 + jq + 0], a0);
            a1 = fmaf(h, w2t[k * 17 + jq + 1], a1);
            a2 = fmaf(h, w2t[k * 17 + jq + 2], a2);
            a3 = fmaf(h, w2t[k * 17 + jq + 3], a3);
        }
        const float dis2 = rsqrtf((float)(rsdeg[node2].y + 1));
        __half2* g2p = (__half2*)(g2h + node2 * 16 + jq);
        g2p[0] = __floats2half2_rn(a0 * dis2, a1 * dis2);
        g2p[1] = __floats2half2_rn(a2 * dis2, a3 * dis2);
    }
}

// ---------------- gather layer 2 + register-lean fused LSTM + head ----------------
__global__ __launch_bounds__(256) void k_gather2(
        const int2* __restrict__ rsdeg,
        const int* __restrict__ col2, const __half* __restrict__ g2h,
        const float* __restrict__ b2,
        const float* __restrict__ w_ih, const float* __restrict__ b_ih,
        const float* __restrict__ b_hh, const float* __restrict__ W_out,
        const float* __restrict__ b_out, float* __restrict__ out) {
    __shared__ __align__(16) float wihs[512];
    __shared__ float bias[32];
    __shared__ float wout[8];
    __shared__ float bo;
    const int t = threadIdx.x;
    for (int idx = t; idx < 512; idx += 256) wihs[idx] = w_ih[idx];
    if (t < 32) bias[t] = b_ih[t] + b_hh[t];
    if (t < 8)  wout[t] = W_out[t];
    if (t == 0) bo = b_out[0];
    __syncthreads();

    const int lane = t & 63, w = t >> 6;
    const int q = lane & 1;
    const int node = blockIdx.x * 128 + w * 32 + (lane >> 1);
    const int nc = node < N ? node : N - 1;
    const int2 rd = rsdeg[nc];
    const int rs = rd.x;
    const int ne = (node < N) ? rd.y : 0;
    const uint4* g2v = (const uint4*)g2h;

    float acc[8];
    {
        uint4 rv = g2v[nc * 2 + q];
        const __half2* hp = (const __half2*)&rv;
#pragma unroll
        for (int m2 = 0; m2 < 4; ++m2) {
            float2 f = __half22float2(hp[m2]);
            acc[2 * m2] = f.x;
            acc[2 * m2 + 1] = f.y;
        }
    }
    int svN[8];
#pragma unroll
    for (int c = 0; c < 8; ++c)
        svN[c] = (2 * c + q < ne) ? col2[rs + 2 * c + q] : 0;
    for (int base = 0; base < ne; base += 16) {
        int sv[8];
#pragma unroll
        for (int c = 0; c < 8; ++c) sv[c] = svN[c];
        const int nb2 = base + 16;
        if (nb2 < ne) {
#pragma unroll
            for (int c = 0; c < 8; ++c)
                svN[c] = (nb2 + 2 * c + q < ne) ? col2[rs + nb2 + 2 * c + q] : 0;
        }
        int idx[16];
#pragma unroll
        for (int c = 0; c < 8; ++c) {
            idx[2 * c]     = min(__shfl(sv[c], 0, 2), N - 1);
            idx[2 * c + 1] = min(__shfl(sv[c], 1, 2), N - 1);
        }
        uint4 rv[16];
#pragma unroll
        for (int u = 0; u < 16; ++u) rv[u] = g2v[idx[u] * 2 + q];
#pragma unroll
        for (int u = 0; u < 16; ++u) {
            float wt = (base + u < ne) ? 1.f : 0.f;
            const __half2* hp = (const __half2*)&rv[u];
#pragma unroll
            for (int m2 = 0; m2 < 4; ++m2) {
                float2 f = __half22float2(hp[m2]);
                acc[2 * m2]     = fmaf(wt, f.x, acc[2 * m2]);
                acc[2 * m2 + 1] = fmaf(wt, f.y, acc[2 * m2 + 1]);
            }
        }
    }
    {
        const float dis = rsqrtf((float)(ne + 1));
#pragma unroll
        for (int u = 0; u < 8; ++u) {
            float v = acc[u] * dis + b2[q * 8 + u];
            acc[u] = v > 0.f ? v : 0.f;
        }
    }
    // LSTM (h0=c0=0) + head, pair-cooperative
    const float4* w4 = (const float4*)wihs;
    float oacc = 0.f;
#pragma unroll
    for (int g = 0; g < 8; ++g) {
        float4 wi0 = w4[g * 4 + q * 2],        wi1 = w4[g * 4 + q * 2 + 1];
        float4 wg0 = w4[(16 + g) * 4 + q * 2], wg1 = w4[(16 + g) * 4 + q * 2 + 1];
        float4 wo0 = w4[(24 + g) * 4 + q * 2], wo1 = w4[(24 + g) * 4 + q * 2 + 1];
        float gi = acc[0] * wi0.x + acc[1] * wi0.y + acc[2] * wi0.z + acc[3] * wi0.w
                 + acc[4] * wi1.x + acc[5] * wi1.y + acc[6] * wi1.z + acc[7] * wi1.w;
        float gg = acc[0] * wg0.x + acc[1] * wg0.y + acc[2] * wg0.z + acc[3] * wg0.w
                 + acc[4] * wg1.x + acc[5] * wg1.y + acc[6] * wg1.z + acc[7] * wg1.w;
        float go = acc[0] * wo0.x + acc[1] * wo0.y + acc[2] * wo0.z + acc[3] * wo0.w
                 + acc[4] * wo1.x + acc[5] * wo1.y + acc[6] * wo1.z + acc[7] * wo1.w;
        gi = gi + __shfl_xor(gi, 1, 2) + bias[g];
        gg = gg + __shfl_xor(gg, 1, 2) + bias[16 + g];
        go = go + __shfl_xor(go, 1, 2) + bias[24 + g];
        float c  = (1.f / (1.f + expf(-gi))) * tanhf(gg);
        float hh = (1.f / (1.f + expf(-go))) * tanhf(c);
        oacc = fmaf(hh, wout[g], oacc);
    }
    if (node < N && q == 0) out[node] = oacc + bo;
}

extern "C" void kernel_launch(void* const* d_in, const int* in_sizes, int n_in,
                              void* d_out, int out_size, void* d_ws, size_t ws_size,
                              hipStream_t stream) {
    const float* x     = (const float*)d_in[0];
    const int*   ei    = (const int*)d_in[1];
    const float* W1    = (const float*)d_in[2];
    const float* b1    = (const float*)d_in[3];
    const float* W2    = (const float*)d_in[4];
    const float* b2    = (const float*)d_in[5];
    const float* w_ih  = (const float*)d_in[6];
    // d_in[7] = w_hh: unused (h0 = 0)
    const float* b_ih  = (const float*)d_in[8];
    const float* b_hh  = (const float*)d_in[9];
    const float* W_out = (const float*)d_in[10];
    const float* b_out = (const float*)d_in[11];
    float* out = (float*)d_out;

    const int E = in_sizes[1] / 2;
    const int* src = ei;
    const int* dst = ei + E;
    int BP = (E + CHUNK - 1) / CHUNK;   // 391
    if (BP > BPMAX) BP = BPMAX;

    // workspace (4 B units); disjoint regions; 16 B alignment maintained
    int* col       = (int*)d_ws;                        // BPMAX*CHUNK
    int* hdr       = col + (size_t)BPMAX * CHUNK;       // BPMAX*HDRS
    int* col2      = hdr + (size_t)BPMAX * HDRS;        // COLCAP
    int* deg       = col2 + COLCAP;                     // N
    int2* rsdeg    = (int2*)(deg + N);                  // N int2 (2N ints)
    int* base2     = deg + N + 2 * N;
    __half* g1h    = (__half*)base2;                      // N*32 halves = N*16 ints
    __half* g2h    = (__half*)(base2 + (size_t)N * 16);   // N*16 halves = N*8 ints

    k_part   <<<BP,              1024, 0, stream>>>(src, dst, col, hdr, E);
    k_sort   <<<NBUCK,           1024, 0, stream>>>(col, hdr, col2, deg, rsdeg, BP);
    k_xw1    <<<N / 32,          256,  0, stream>>>(x, W1, deg, g1h);
    k_gather1<<<(N + 63) / 64,   256,  0, stream>>>(rsdeg, col2, g1h, b1, W2, g2h);
    k_gather2<<<(N + 127) / 128, 256,  0, stream>>>(rsdeg, col2, g2h, b2,
                                                    w_ih, b_ih, b_hh, W_out, b_out, out);
}

// Round 19
// 229.909 us; speedup vs baseline: 1.1382x; 1.0034x over previous
//
#include <hip/hip_runtime.h>
#include <hip/hip_fp16.h>
#include <math.h>

static constexpr int N = 100000;
static constexpr int SHIFT = 7;                        // 128 nodes / bucket
static constexpr int BUCKN = 1 << SHIFT;               // 128
static constexpr int NBUCK = (N + BUCKN - 1) >> SHIFT; // 782
static constexpr int HDRS  = NBUCK + 1;                // 783 offsets per block
static constexpr int CHUNK = 8192;                     // edges per partition block
static constexpr int BPMAX = 512;                      // max partition blocks supported
static constexpr int STRIDE = 5120;                    // per-bucket CSR capacity (16 sigma)
static constexpr int COLCAP = NBUCK * STRIDE;
static constexpr int ES_CAP = STRIDE;

// inclusive block scan over 1024 threads via wave shuffles
__device__ __forceinline__ int block_scan_incl(int v, int* wtot, int t) {
    const int lane = t & 63, wv = t >> 6;
    int x = v;
#pragma unroll
    for (int o = 1; o < 64; o <<= 1) {
        int y = __shfl_up(x, o, 64);
        if (lane >= o) x += y;
    }
    __syncthreads();                 // protect wtot reuse across calls
    if (lane == 63) wtot[wv] = x;
    __syncthreads();
    if (t < 16) {
        int y = wtot[t];
#pragma unroll
        for (int o = 1; o < 16; o <<= 1) {
            int z = __shfl_up(y, o, 16);
            if (t >= o) y += z;
        }
        wtot[t] = y;
    }
    __syncthreads();
    return x + (wv ? wtot[wv - 1] : 0);
}

// ---------------- partition: per-block LDS counting sort, COALESCED + int4 I/O ----------------
__global__ __launch_bounds__(1024) void k_part(const int* __restrict__ src,
                                               const int* __restrict__ dst,
                                               int* __restrict__ col,
                                               int* __restrict__ hdr, int E) {
    __shared__ __align__(16) int stage[CHUNK];     // 32 KB
    __shared__ int hl[NBUCK];
    __shared__ int cur[NBUCK];
    __shared__ int wtot[16];
    const int t = threadIdx.x, b = blockIdx.x;
    if (t < NBUCK) hl[t] = 0;        // 1024 >= NBUCK: single-shot OK
    __syncthreads();
    const int e0 = b * CHUNK;
    const int m = min(CHUNK, E - e0);
    const int m4 = m >> 2;
    const int4* d4 = (const int4*)(dst + e0);
    for (int i = t; i < m4; i += 1024) {
        int4 d = d4[i];
        atomicAdd(&hl[d.x >> SHIFT], 1);
        atomicAdd(&hl[d.y >> SHIFT], 1);
        atomicAdd(&hl[d.z >> SHIFT], 1);
        atomicAdd(&hl[d.w >> SHIFT], 1);
    }
    for (int i = (m4 << 2) + t; i < m; i += 1024) atomicAdd(&hl[dst[e0 + i] >> SHIFT], 1);
    __syncthreads();
    const int v = (t < NBUCK) ? hl[t] : 0;
    const int inc = block_scan_incl(v, wtot, t);
    if (t < NBUCK) {
        int excl = inc - v;
        cur[t] = excl;
        hdr[b * HDRS + t] = excl;
    }
    if (t == 0) hdr[b * HDRS + NBUCK] = m;
    __syncthreads();
    const int4* s4 = (const int4*)(src + e0);
    for (int i = t; i < m4; i += 1024) {
        int4 d = d4[i];
        int4 s = s4[i];
        int p;
        p = atomicAdd(&cur[d.x >> SHIFT], 1); p = min(max(p, 0), CHUNK - 1);
        stage[p] = (s.x & 0x1FFFF) | ((d.x & (BUCKN - 1)) << 17);
        p = atomicAdd(&cur[d.y >> SHIFT], 1); p = min(max(p, 0), CHUNK - 1);
        stage[p] = (s.y & 0x1FFFF) | ((d.y & (BUCKN - 1)) << 17);
        p = atomicAdd(&cur[d.z >> SHIFT], 1); p = min(max(p, 0), CHUNK - 1);
        stage[p] = (s.z & 0x1FFFF) | ((d.z & (BUCKN - 1)) << 17);
        p = atomicAdd(&cur[d.w >> SHIFT], 1); p = min(max(p, 0), CHUNK - 1);
        stage[p] = (s.w & 0x1FFFF) | ((d.w & (BUCKN - 1)) << 17);
    }
    for (int i = (m4 << 2) + t; i < m; i += 1024) {
        int d = dst[e0 + i];
        int p = atomicAdd(&cur[d >> SHIFT], 1);
        p = min(max(p, 0), CHUNK - 1);
        stage[p] = (src[e0 + i] & 0x1FFFF) | ((d & (BUCKN - 1)) << 17);
    }
    __syncthreads();
    int4* c4 = (int4*)(col + e0);
    const int4* st4 = (const int4*)stage;
    for (int i = t; i < m4; i += 1024) c4[i] = st4[i];              // sequential 16 B
    for (int i = (m4 << 2) + t; i < m; i += 1024) col[e0 + i] = stage[i];
}

// ---------------- per-bucket: gather runs, sort in LDS, SEQUENTIAL col2 writeback ----------------
__global__ __launch_bounds__(1024) void k_sort(const int* __restrict__ col,
                                               const int* __restrict__ hdr,
                                               int* __restrict__ col2,
                                               int* __restrict__ deg,
                                               int2* __restrict__ rsdeg, int BP) {
    __shared__ int es[ES_CAP];                 // 20 KB
    __shared__ __align__(16) int es2[ES_CAP];  // 20 KB (sorted output staging)
    __shared__ int rlen[BPMAX];
    __shared__ int rst[BPMAX];
    __shared__ int roff[BPMAX];
    __shared__ int cnt[BUCKN];
    __shared__ int cur[BUCKN];
    __shared__ int wtot[16];
    __shared__ int ntot;
    const int t = threadIdx.x, buck = blockIdx.x;
    if (t < BPMAX) { rlen[t] = 0; rst[t] = 0; }
    __syncthreads();
    if (t < BP) {
        int a = hdr[t * HDRS + buck];
        int e = hdr[t * HDRS + buck + 1];
        rst[t] = min(max(a, 0), CHUNK);
        rlen[t] = min(max(e - a, 0), CHUNK);
    }
    __syncthreads();
    {
        const int v = (t < BPMAX) ? rlen[t] : 0;
        const int inc = block_scan_incl(v, wtot, t);
        if (t < BPMAX) roff[t] = inc - v;
        if (t == 1023) ntot = min(inc, ES_CAP);
    }
    __syncthreads();
    const int n = ntot;
    {   // cooperative run copy: 64 groups x 16 lanes
        const int g = t >> 4, l = t & 15;
        for (int r = g; r < BP; r += 64) {
            const int len = rlen[r];
            const int base = r * CHUNK + rst[r];
            const int o = roff[r];
            for (int k = l; k < len; k += 16) {
                int p = o + k;
                if (p < ES_CAP) es[p] = col[base + k];
            }
        }
    }
    __syncthreads();
    if (t < BUCKN) cnt[t] = 0;
    __syncthreads();
    for (int i = t; i < n; i += 1024) atomicAdd(&cnt[(es[i] >> 17) & (BUCKN - 1)], 1);
    __syncthreads();
    {
        const int v = (t < BUCKN) ? cnt[t] : 0;
        const int inc = block_scan_incl(v, wtot, t);
        if (t < BUCKN) {
            int excl = inc - v;
            int node = buck * BUCKN + t;
            if (node < N) {
                deg[node] = v;
                rsdeg[node] = make_int2(buck * STRIDE + excl, v);
            }
            cur[t] = excl;
        }
    }
    __syncthreads();
    for (int i = t; i < n; i += 1024) {          // scatter within LDS (cheap)
        int p = es[i];
        int pos = atomicAdd(&cur[(p >> 17) & (BUCKN - 1)], 1);
        pos = min(max(pos, 0), ES_CAP - 1);
        es2[pos] = p & 0x1FFFF;
    }
    __syncthreads();
    {   // sequential int4 writeback
        const int n4 = n >> 2;
        int4* o4 = (int4*)(col2 + buck * STRIDE);
        const int4* e4 = (const int4*)es2;
        for (int i = t; i < n4; i += 1024) o4[i] = e4[i];
        for (int i = (n4 << 2) + t; i < n; i += 1024) col2[buck * STRIDE + i] = es2[i];
    }
}

// ---------------- layer 1 transform: g1h = fp16( dis * (x @ W1^T) ) ----------------
__global__ __launch_bounds__(256) void k_xw1(
        const float* __restrict__ x, const float* __restrict__ W1,
        const int* __restrict__ deg, __half* __restrict__ g1h) {
    __shared__ float4 wtv[32 * 33];   // [kb][j] quad of W1[j][4kb..4kb+3], pad 33
    __shared__ float4 xsv[1024];      // 32 nodes x 32 k-quads
    const int t = threadIdx.x;
    const float4* W1v = (const float4*)W1;
    for (int idx = t; idx < 1024; idx += 256) {
        int j = idx >> 5, kb = idx & 31;
        wtv[kb * 33 + j] = W1v[idx];
    }
    const float4* x4 = (const float4*)x + (size_t)blockIdx.x * 1024;
    for (int idx = t; idx < 1024; idx += 256) xsv[idx] = x4[idx];
    __syncthreads();

    const int j = t & 31, ng = t >> 5;
    float a0 = 0.f, a1 = 0.f, a2 = 0.f, a3 = 0.f;
#pragma unroll 4
    for (int kb = 0; kb < 32; ++kb) {
        float4 w = wtv[kb * 33 + j];
        float4 x0 = xsv[(4 * ng + 0) * 32 + kb];
        float4 x1 = xsv[(4 * ng + 1) * 32 + kb];
        float4 x2 = xsv[(4 * ng + 2) * 32 + kb];
        float4 x3 = xsv[(4 * ng + 3) * 32 + kb];
        a0 = fmaf(w.x, x0.x, fmaf(w.y, x0.y, fmaf(w.z, x0.z, fmaf(w.w, x0.w, a0))));
        a1 = fmaf(w.x, x1.x, fmaf(w.y, x1.y, fmaf(w.z, x1.z, fmaf(w.w, x1.w, a1))));
        a2 = fmaf(w.x, x2.x, fmaf(w.y, x2.y, fmaf(w.z, x2.z, fmaf(w.w, x2.w, a2))));
        a3 = fmaf(w.x, x3.x, fmaf(w.y, x3.y, fmaf(w.z, x3.z, fmaf(w.w, x3.w, a3))));
    }
    const int nb = blockIdx.x * 32 + 4 * ng;
    g1h[(nb + 0) * 32 + j] = __float2half(a0 * rsqrtf((float)(deg[nb + 0] + 1)));
    g1h[(nb + 1) * 32 + j] = __float2half(a1 * rsqrtf((float)(deg[nb + 1] + 1)));
    g1h[(nb + 2) * 32 + j] = __float2half(a2 * rsqrtf((float)(deg[nb + 2] + 1)));
    g1h[(nb + 3) * 32 + j] = __float2half(a3 * rsqrtf((float)(deg[nb + 3] + 1)));
}

// ---------------- gather layer 1 + FUSED layer-2 transform (lean tail) ----------------
// __launch_bounds__(256,4): allow up to ~128 VGPR so the 16-load window truly
// stays in flight (round-15 counters showed VGPR=40 -> compiler had serialized
// the window into ~6-load batches; kernel is latency-bound with occupancy to spare).
__global__ __launch_bounds__(256, 4) void k_gather1(
        const int2* __restrict__ rsdeg,
        const int* __restrict__ col2, const __half* __restrict__ g1h,
        const float* __restrict__ b1, const float* __restrict__ W2,
        __half* __restrict__ g2h) {
    __shared__ float h1s[64 * 33];   // 8.4 KB, pad 33
    __shared__ float w2t[32 * 17];   // W2 transposed [k][j], pad 17
    const int t = threadIdx.x;
    for (int idx = t; idx < 512; idx += 256) {
        int j = idx >> 5, k = idx & 31;
        w2t[k * 17 + j] = W2[idx];
    }
    const int lane = t & 63, w = t >> 6;
    const int q = lane & 3;                      // feature octet
    const int nloc = w * 16 + (lane >> 2);
    const int node = blockIdx.x * 64 + nloc;
    const int nc = node < N ? node : N - 1;
    const int2 rd = rsdeg[nc];
    const int rs = rd.x;
    const int ne = (node < N) ? rd.y : 0;
    const uint4* g1v = (const uint4*)g1h;

    float acc[8];
    {
        uint4 rv = g1v[nc * 4 + q];
        const __half2* hp = (const __half2*)&rv;
#pragma unroll
        for (int m2 = 0; m2 < 4; ++m2) {
            float2 f = __half22float2(hp[m2]);
            acc[2 * m2] = f.x;
            acc[2 * m2 + 1] = f.y;
        }
    }
    int svN[4];
#pragma unroll
    for (int c = 0; c < 4; ++c)
        svN[c] = (4 * c + q < ne) ? col2[rs + 4 * c + q] : 0;
    for (int base = 0; base < ne; base += 16) {
        int sv[4];
#pragma unroll
        for (int c = 0; c < 4; ++c) sv[c] = svN[c];
        const int nb2 = base + 16;
        if (nb2 < ne) {
#pragma unroll
            for (int c = 0; c < 4; ++c)
                svN[c] = (nb2 + 4 * c + q < ne) ? col2[rs + nb2 + 4 * c + q] : 0;
        }
        int idx[16];
#pragma unroll
        for (int c = 0; c < 4; ++c)
#pragma unroll
            for (int u = 0; u < 4; ++u)
                idx[4 * c + u] = min(__shfl(sv[c], u, 4), N - 1);
        uint4 rv[16];
#pragma unroll
        for (int u = 0; u < 16; ++u) rv[u] = g1v[idx[u] * 4 + q];
#pragma unroll
        for (int u = 0; u < 16; ++u) {
            float wt = (base + u < ne) ? 1.f : 0.f;
            const __half2* hp = (const __half2*)&rv[u];
#pragma unroll
            for (int m2 = 0; m2 < 4; ++m2) {
                float2 f = __half22float2(hp[m2]);
                acc[2 * m2]     = fmaf(wt, f.x, acc[2 * m2]);
                acc[2 * m2 + 1] = fmaf(wt, f.y, acc[2 * m2 + 1]);
            }
        }
    }
    {
        const float dis = rsqrtf((float)(ne + 1));
#pragma unroll
        for (int u = 0; u < 8; ++u) {
            float v = (node < N) ? (acc[u] * dis + b1[q * 8 + u]) : 0.f;
            h1s[nloc * 33 + q * 8 + u] = v > 0.f ? v : 0.f;
        }
    }
    __syncthreads();
    const int n2 = t >> 2, jq = (t & 3) * 4;
    const int node2 = blockIdx.x * 64 + n2;
    if (node2 < N) {
        float a0 = 0.f, a1 = 0.f, a2 = 0.f, a3 = 0.f;
        const float* hr = h1s + n2 * 33;
#pragma unroll
        for (int k = 0; k < 32; ++k) {
            float h = hr[k];
            a0 = fmaf(h, w2t[k * 17 + jq + 0], a0);
            a1 = fmaf(h, w2t[k * 17 + jq + 1], a1);
            a2 = fmaf(h, w2t[k * 17 + jq + 2], a2);
            a3 = fmaf(h, w2t[k * 17 + jq + 3], a3);
        }
        const float dis2 = rsqrtf((float)(rsdeg[node2].y + 1));
        __half2* g2p = (__half2*)(g2h + node2 * 16 + jq);
        g2p[0] = __floats2half2_rn(a0 * dis2, a1 * dis2);
        g2p[1] = __floats2half2_rn(a2 * dis2, a3 * dis2);
    }
}

// ---------------- gather layer 2 + register-lean fused LSTM + head ----------------
__global__ __launch_bounds__(256, 4) void k_gather2(
        const int2* __restrict__ rsdeg,
        const int* __restrict__ col2, const __half* __restrict__ g2h,
        const float* __restrict__ b2,
        const float* __restrict__ w_ih, const float* __restrict__ b_ih,
        const float* __restrict__ b_hh, const float* __restrict__ W_out,
        const float* __restrict__ b_out, float* __restrict__ out) {
    __shared__ __align__(16) float wihs[512];
    __shared__ float bias[32];
    __shared__ float wout[8];
    __shared__ float bo;
    const int t = threadIdx.x;
    for (int idx = t; idx < 512; idx += 256) wihs[idx] = w_ih[idx];
    if (t < 32) bias[t] = b_ih[t] + b_hh[t];
    if (t < 8)  wout[t] = W_out[t];
    if (t == 0) bo = b_out[0];
    __syncthreads();

    const int lane = t & 63, w = t >> 6;
    const int q = lane & 1;
    const int node = blockIdx.x * 128 + w * 32 + (lane >> 1);
    const int nc = node < N ? node : N - 1;
    const int2 rd = rsdeg[nc];
    const int rs = rd.x;
    const int ne = (node < N) ? rd.y : 0;
    const uint4* g2v = (const uint4*)g2h;

    float acc[8];
    {
        uint4 rv = g2v[nc * 2 + q];
        const __half2* hp = (const __half2*)&rv;
#pragma unroll
        for (int m2 = 0; m2 < 4; ++m2) {
            float2 f = __half22float2(hp[m2]);
            acc[2 * m2] = f.x;
            acc[2 * m2 + 1] = f.y;
        }
    }
    int svN[8];
#pragma unroll
    for (int c = 0; c < 8; ++c)
        svN[c] = (2 * c + q < ne) ? col2[rs + 2 * c + q] : 0;
    for (int base = 0; base < ne; base += 16) {
        int sv[8];
#pragma unroll
        for (int c = 0; c < 8; ++c) sv[c] = svN[c];
        const int nb2 = base + 16;
        if (nb2 < ne) {
#pragma unroll
            for (int c = 0; c < 8; ++c)
                svN[c] = (nb2 + 2 * c + q < ne) ? col2[rs + nb2 + 2 * c + q] : 0;
        }
        int idx[16];
#pragma unroll
        for (int c = 0; c < 8; ++c) {
            idx[2 * c]     = min(__shfl(sv[c], 0, 2), N - 1);
            idx[2 * c + 1] = min(__shfl(sv[c], 1, 2), N - 1);
        }
        uint4 rv[16];
#pragma unroll
        for (int u = 0; u < 16; ++u) rv[u] = g2v[idx[u] * 2 + q];
#pragma unroll
        for (int u = 0; u < 16; ++u) {
            float wt = (base + u < ne) ? 1.f : 0.f;
            const __half2* hp = (const __half2*)&rv[u];
#pragma unroll
            for (int m2 = 0; m2 < 4; ++m2) {
                float2 f = __half22float2(hp[m2]);
                acc[2 * m2]     = fmaf(wt, f.x, acc[2 * m2]);
                acc[2 * m2 + 1] = fmaf(wt, f.y, acc[2 * m2 + 1]);
            }
        }
    }
    {
        const float dis = rsqrtf((float)(ne + 1));
#pragma unroll
        for (int u = 0; u < 8; ++u) {
            float v = acc[u] * dis + b2[q * 8 + u];
            acc[u] = v > 0.f ? v : 0.f;
        }
    }
    // LSTM (h0=c0=0) + head, pair-cooperative
    const float4* w4 = (const float4*)wihs;
    float oacc = 0.f;
#pragma unroll
    for (int g = 0; g < 8; ++g) {
        float4 wi0 = w4[g * 4 + q * 2],        wi1 = w4[g * 4 + q * 2 + 1];
        float4 wg0 = w4[(16 + g) * 4 + q * 2], wg1 = w4[(16 + g) * 4 + q * 2 + 1];
        float4 wo0 = w4[(24 + g) * 4 + q * 2], wo1 = w4[(24 + g) * 4 + q * 2 + 1];
        float gi = acc[0] * wi0.x + acc[1] * wi0.y + acc[2] * wi0.z + acc[3] * wi0.w
                 + acc[4] * wi1.x + acc[5] * wi1.y + acc[6] * wi1.z + acc[7] * wi1.w;
        float gg = acc[0] * wg0.x + acc[1] * wg0.y + acc[2] * wg0.z + acc[3] * wg0.w
                 + acc[4] * wg1.x + acc[5] * wg1.y + acc[6] * wg1.z + acc[7] * wg1.w;
        float go = acc[0] * wo0.x + acc[1] * wo0.y + acc[2] * wo0.z + acc[3] * wo0.w
                 + acc[4] * wo1.x + acc[5] * wo1.y + acc[6] * wo1.z + acc[7] * wo1.w;
        gi = gi + __shfl_xor(gi, 1, 2) + bias[g];
        gg = gg + __shfl_xor(gg, 1, 2) + bias[16 + g];
        go = go + __shfl_xor(go, 1, 2) + bias[24 + g];
        float c  = (1.f / (1.f + expf(-gi))) * tanhf(gg);
        float hh = (1.f / (1.f + expf(-go))) * tanhf(c);
        oacc = fmaf(hh, wout[g], oacc);
    }
    if (node < N && q == 0) out[node] = oacc + bo;
}

extern "C" void kernel_launch(void* const* d_in, const int* in_sizes, int n_in,
                              void* d_out, int out_size, void* d_ws, size_t ws_size,
                              hipStream_t stream) {
    const float* x     = (const float*)d_in[0];
    const int*   ei    = (const int*)d_in[1];
    const float* W1    = (const float*)d_in[2];
    const float* b1    = (const float*)d_in[3];
    const float* W2    = (const float*)d_in[4];
    const float* b2    = (const float*)d_in[5];
    const float* w_ih  = (const float*)d_in[6];
    // d_in[7] = w_hh: unused (h0 = 0)
    const float* b_ih  = (const float*)d_in[8];
    const float* b_hh  = (const float*)d_in[9];
    const float* W_out = (const float*)d_in[10];
    const float* b_out = (const float*)d_in[11];
    float* out = (float*)d_out;

    const int E = in_sizes[1] / 2;
    const int* src = ei;
    const int* dst = ei + E;
    int BP = (E + CHUNK - 1) / CHUNK;   // 391
    if (BP > BPMAX) BP = BPMAX;

    // workspace (4 B units); disjoint regions; 16 B alignment maintained
    int* col       = (int*)d_ws;                        // BPMAX*CHUNK
    int* hdr       = col + (size_t)BPMAX * CHUNK;       // BPMAX*HDRS
    int* col2      = hdr + (size_t)BPMAX * HDRS;        // COLCAP
    int* deg       = col2 + COLCAP;                     // N
    int2* rsdeg    = (int2*)(deg + N);                  // N int2 (2N ints)
    int* base2     = deg + N + 2 * N;
    __half* g1h    = (__half*)base2;                      // N*32 halves = N*16 ints
    __half* g2h    = (__half*)(base2 + (size_t)N * 16);   // N*16 halves = N*8 ints

    k_part   <<<BP,              1024, 0, stream>>>(src, dst, col, hdr, E);
    k_sort   <<<NBUCK,           1024, 0, stream>>>(col, hdr, col2, deg, rsdeg, BP);
    k_xw1    <<<N / 32,          256,  0, stream>>>(x, W1, deg, g1h);
    k_gather1<<<(N + 63) / 64,   256,  0, stream>>>(rsdeg, col2, g1h, b1, W2, g2h);
    k_gather2<<<(N + 127) / 128, 256,  0, stream>>>(rsdeg, col2, g2h, b2,
                                                    w_ih, b_ih, b_hh, W_out, b_out, out);
}